// Round 9
// baseline (312.755 us; speedup 1.0000x reference)
//
#include <hip/hip_runtime.h>
#include <hip/hip_bf16.h>
#include <math.h>

#define N_NODES 20000
#define EMB 128
#define HID 64
#define RELS 8
#define CLS 16
#define N_EDGES 640000
#define NEG 0.2f
#define NKEYS (N_NODES * RELS)
#define SCAN_CHUNK 1024
#define SCAN_NBLK ((NKEYS + SCAN_CHUNK - 1) / SCAN_CHUNK)  // 157
#define RCAP 80    // staged x-rows per (block, rel) phase
#define ECAP 144   // staged srcs/weights per (block, rel) phase

typedef unsigned short ushort_t;
typedef __attribute__((ext_vector_type(8))) short bf16x8;
typedef __attribute__((ext_vector_type(8))) unsigned short ushort8_t;
typedef __attribute__((ext_vector_type(4))) unsigned short ushort4_t;
typedef __attribute__((ext_vector_type(4))) float f32x4;

__device__ __forceinline__ float b2f(ushort_t u) {
    return __uint_as_float(((unsigned int)u) << 16);
}
__device__ __forceinline__ ushort_t f2b(float f) {
    __hip_bfloat16 h = __float2bfloat16(f);
    return *reinterpret_cast<ushort_t*>(&h);
}

// ---------------- f32 -> bf16 conversion ----------------
__global__ __launch_bounds__(256) void k_cvt(const float* __restrict__ in, ushort_t* __restrict__ outp, int n4) {
    int i = blockIdx.x * blockDim.x + threadIdx.x;
    if (i >= n4) return;
    float4 v = *(const float4*)&in[(size_t)i * 4];
    ushort4 o;
    o.x = f2b(v.x); o.y = f2b(v.y); o.z = f2b(v.z); o.w = f2b(v.w);
    *(ushort4*)&outp[(size_t)i * 4] = o;
}

// ---------------- Wqk precompute ----------------
template <int D, int OUT>
__global__ __launch_bounds__(256) void k_wqk(const float* __restrict__ w, const float* __restrict__ q,
                                             const float* __restrict__ k, ushort_t* __restrict__ wqkt) {
    int tid = blockIdx.x * blockDim.x + threadIdx.x;
    if (tid >= 48 * D) return;
    int c = tid / D, i = tid % D;
    int r = c / 6, j = c % 6;
    const float* qk = (j < 3) ? q : k;
    int jj = (j < 3) ? j : j - 3;
    const float* wrow = w + ((size_t)r * D + i) * OUT;
    float s = 0.f;
    for (int o = 0; o < OUT; o++) s += wrow[o] * qk[o * 3 + jj];
    wqkt[(size_t)c * D + i] = f2b(s);
}

// ---------------- Wagg precompute: Bt[o][(r*3+h)*D + i] = w[r][i][h*OC + o] ----------------
template <int D, int OC>
__global__ __launch_bounds__(256) void k_wagg(const float* __restrict__ w, ushort_t* __restrict__ outp) {
    const int KT = RELS * 3 * D;
    int tid = blockIdx.x * blockDim.x + threadIdx.x;
    if (tid >= OC * KT) return;
    int o = tid / KT, kidx = tid % KT;
    int r = kidx / (3 * D), h = (kidx / D) % 3, i = kidx % D;
    float v = w[((size_t)r * D + i) * (3 * OC) + h * OC + o];
    outp[tid] = f2b(v);
}

// ---------------- CSR build over keys = dst*8 + rel ----------------
__global__ __launch_bounds__(256) void k_count(const int* __restrict__ dst, const int* __restrict__ et,
                                               int* __restrict__ counts) {
    int e = blockIdx.x * blockDim.x + threadIdx.x;
    if (e < N_EDGES) atomicAdd(&counts[dst[e] * 8 + et[e]], 1);
}

__global__ __launch_bounds__(256) void k_scanA(const int* __restrict__ counts, int* __restrict__ keyoff,
                                               int* __restrict__ blocksum) {
    __shared__ int part[256];
    int b = blockIdx.x, tid = threadIdx.x;
    int base = b * SCAN_CHUNK + tid * 4;
    int4 c = make_int4(0, 0, 0, 0);
    if (base + 3 < NKEYS) c = *(const int4*)&counts[base];
    else {
        if (base + 0 < NKEYS) c.x = counts[base + 0];
        if (base + 1 < NKEYS) c.y = counts[base + 1];
        if (base + 2 < NKEYS) c.z = counts[base + 2];
        if (base + 3 < NKEYS) c.w = counts[base + 3];
    }
    int s = c.x + c.y + c.z + c.w;
    part[tid] = s;
    __syncthreads();
    for (int off = 1; off < 256; off <<= 1) {
        int v = (tid >= off) ? part[tid - off] : 0;
        __syncthreads();
        part[tid] += v;
        __syncthreads();
    }
    int excl = part[tid] - s;
    int4 o;
    o.x = excl;
    o.y = excl + c.x;
    o.z = excl + c.x + c.y;
    o.w = excl + c.x + c.y + c.z;
    if (base + 3 < NKEYS) *(int4*)&keyoff[base] = o;
    else {
        if (base + 0 < NKEYS) keyoff[base + 0] = o.x;
        if (base + 1 < NKEYS) keyoff[base + 1] = o.y;
        if (base + 2 < NKEYS) keyoff[base + 2] = o.z;
        if (base + 3 < NKEYS) keyoff[base + 3] = o.w;
    }
    if (tid == 255) blocksum[b] = part[255];
}

__global__ __launch_bounds__(256) void k_scanB(int* __restrict__ blocksum, int* __restrict__ blockbase,
                                               int* __restrict__ keyoff) {
    __shared__ int part[256];
    int tid = threadIdx.x;
    int v0 = (tid < SCAN_NBLK) ? blocksum[tid] : 0;
    part[tid] = v0;
    __syncthreads();
    for (int off = 1; off < 256; off <<= 1) {
        int v = (tid >= off) ? part[tid - off] : 0;
        __syncthreads();
        part[tid] += v;
        __syncthreads();
    }
    if (tid < SCAN_NBLK) blockbase[tid] = part[tid] - v0;
    if (tid == 255) keyoff[NKEYS] = part[255];
}

__global__ __launch_bounds__(256) void k_scanC(const int* __restrict__ blockbase, int* __restrict__ keyoff,
                                               int* __restrict__ cursor) {
    int b = blockIdx.x, tid = threadIdx.x;
    int base = b * SCAN_CHUNK + tid * 4;
    int add = blockbase[b];
    if (base + 3 < NKEYS) {
        int4 v = *(const int4*)&keyoff[base];
        v.x += add; v.y += add; v.z += add; v.w += add;
        *(int4*)&keyoff[base] = v;
        *(int4*)&cursor[base] = v;
    } else {
        for (int j = 0; j < 4; j++) {
            if (base + j < NKEYS) {
                int v = keyoff[base + j] + add;
                keyoff[base + j] = v;
                cursor[base + j] = v;
            }
        }
    }
}

// ---------------- scatter srcs into CSR order ----------------
__global__ __launch_bounds__(256) void k_scatter(const int* __restrict__ src, const int* __restrict__ dst,
                                                 const int* __restrict__ et, int* __restrict__ cursor,
                                                 int* __restrict__ srcs) {
    int e = blockIdx.x * blockDim.x + threadIdx.x;
    if (e < N_EDGES) {
        int p = atomicAdd(&cursor[dst[e] * 8 + et[e]], 1);
        srcs[p] = src[e];
    }
}

// ---------------- direct-fragment MFMA GEMM (qkd projections) ----------------
template <int K, int KCH, int N, int MREP, int NREP>
__global__ __launch_bounds__(256) void k_mfma_gemm(const ushort_t* __restrict__ A, const ushort_t* __restrict__ Bt,
                                                   float* __restrict__ outp, int M) {
    const int wid = threadIdx.x >> 6;
    const int lane = threadIdx.x & 63;
    const int m0 = blockIdx.x * (4 * MREP * 16) + wid * (MREP * 16);
    const int kbase = blockIdx.y * KCH;
    const int l15 = lane & 15;
    const int kq = (lane >> 4) * 8;

    f32x4 acc[MREP][NREP] = {};
    for (int kk = kbase; kk < kbase + KCH; kk += 32) {
        bf16x8 a[MREP], b[NREP];
#pragma unroll
        for (int i = 0; i < MREP; i++) {
            int row = m0 + i * 16 + l15;
            row = row < M ? row : M - 1;
            a[i] = *(const bf16x8*)&A[(size_t)row * K + kk + kq];
        }
#pragma unroll
        for (int j = 0; j < NREP; j++) b[j] = *(const bf16x8*)&Bt[(size_t)(j * 16 + l15) * K + kk + kq];
#pragma unroll
        for (int i = 0; i < MREP; i++)
#pragma unroll
            for (int j = 0; j < NREP; j++)
                acc[i][j] = __builtin_amdgcn_mfma_f32_16x16x32_bf16(a[i], b[j], acc[i][j], 0, 0, 0);
    }
    float* op = outp + (size_t)blockIdx.y * M * N;
    const int r4 = (lane >> 4) * 4;
#pragma unroll
    for (int i = 0; i < MREP; i++) {
#pragma unroll
        for (int j = 0; j < NREP; j++) {
#pragma unroll
            for (int g = 0; g < 4; g++) {
                int row = m0 + i * 16 + r4 + g;
                if (row < M) op[(size_t)row * N + j * 16 + l15] = acc[i][j][g];
            }
        }
    }
}

// ---------------- per-edge alpha from qkd (on the fly) ----------------
__device__ __forceinline__ void edge_alpha(int s_idx, const int (&ko)[9], const int* __restrict__ srcs,
                                           const float* __restrict__ qkd, const float* __restrict__ qbase,
                                           float& a0, float& a1, float& a2) {
    int r = 0;
#pragma unroll
    for (int j = 1; j < 8; j++) r += (s_idx >= ko[j]) ? 1 : 0;
    int sv = srcs[s_idx];
    const float* kd = qkd + (size_t)sv * 48 + r * 6 + 3;
    const float* qd = qbase + r * 6;
    float t0 = qd[0] + kd[0], t1 = qd[1] + kd[1], t2 = qd[2] + kd[2];
    a0 = t0 > 0.f ? t0 : NEG * t0;
    a1 = t1 > 0.f ? t1 : NEG * t1;
    a2 = t2 > 0.f ? t2 : NEG * t2;
}

// ---------------- softmax stats (alpha fused in) -> normalized weights ----------------
__global__ __launch_bounds__(256) void k_stats(const int* __restrict__ keyoff, const int* __restrict__ srcs,
                                               const float* __restrict__ qkd, float* __restrict__ wcsr) {
    int node = blockIdx.x * 4 + (threadIdx.x >> 6);
    int lane = threadIdx.x & 63;
    int ko[9];
#pragma unroll
    for (int j = 0; j < 9; j++) ko[j] = keyoff[node * 8 + j];
    int beg = ko[0], end = ko[8], deg = end - beg;
    if (deg == 0) return;
    const float* qbase = qkd + (size_t)node * 48;

    if (deg <= 64) {
        float a0 = -INFINITY, a1 = -INFINITY, a2 = -INFINITY;
        if (lane < deg) edge_alpha(beg + lane, ko, srcs, qkd, qbase, a0, a1, a2);
        float m0 = a0, m1 = a1, m2 = a2;
#pragma unroll
        for (int off = 32; off >= 1; off >>= 1) {
            m0 = fmaxf(m0, __shfl_xor(m0, off));
            m1 = fmaxf(m1, __shfl_xor(m1, off));
            m2 = fmaxf(m2, __shfl_xor(m2, off));
        }
        float e0 = 0.f, e1 = 0.f, e2 = 0.f;
        if (lane < deg) {
            e0 = expf(a0 - m0);
            e1 = expf(a1 - m1);
            e2 = expf(a2 - m2);
        }
        float s0 = e0, s1 = e1, s2 = e2;
#pragma unroll
        for (int off = 32; off >= 1; off >>= 1) {
            s0 += __shfl_xor(s0, off);
            s1 += __shfl_xor(s1, off);
            s2 += __shfl_xor(s2, off);
        }
        float i0 = 1.f / (3.f * (s0 + 1e-16f));
        float i1 = 1.f / (3.f * (s1 + 1e-16f));
        float i2 = 1.f / (3.f * (s2 + 1e-16f));
        if (lane < deg) {
            size_t p = (size_t)(beg + lane) * 3;
            wcsr[p + 0] = e0 * i0;
            wcsr[p + 1] = e1 * i1;
            wcsr[p + 2] = e2 * i2;
        }
    } else {
        float m0 = -INFINITY, m1 = -INFINITY, m2 = -INFINITY;
        for (int i = beg + lane; i < end; i += 64) {
            float a0, a1, a2;
            edge_alpha(i, ko, srcs, qkd, qbase, a0, a1, a2);
            m0 = fmaxf(m0, a0); m1 = fmaxf(m1, a1); m2 = fmaxf(m2, a2);
        }
#pragma unroll
        for (int off = 32; off >= 1; off >>= 1) {
            m0 = fmaxf(m0, __shfl_xor(m0, off));
            m1 = fmaxf(m1, __shfl_xor(m1, off));
            m2 = fmaxf(m2, __shfl_xor(m2, off));
        }
        float s0 = 0.f, s1 = 0.f, s2 = 0.f;
        for (int i = beg + lane; i < end; i += 64) {
            float a0, a1, a2;
            edge_alpha(i, ko, srcs, qkd, qbase, a0, a1, a2);
            s0 += expf(a0 - m0); s1 += expf(a1 - m1); s2 += expf(a2 - m2);
        }
#pragma unroll
        for (int off = 32; off >= 1; off >>= 1) {
            s0 += __shfl_xor(s0, off);
            s1 += __shfl_xor(s1, off);
            s2 += __shfl_xor(s2, off);
        }
        float i0 = 1.f / (3.f * (s0 + 1e-16f));
        float i1 = 1.f / (3.f * (s1 + 1e-16f));
        float i2 = 1.f / (3.f * (s2 + 1e-16f));
        for (int i = beg + lane; i < end; i += 64) {
            float a0, a1, a2;
            edge_alpha(i, ko, srcs, qkd, qbase, a0, a1, a2);
            wcsr[(size_t)i * 3 + 0] = expf(a0 - m0) * i0;
            wcsr[(size_t)i * 3 + 1] = expf(a1 - m1) * i1;
            wcsr[(size_t)i * 3 + 2] = expf(a2 - m2) * i2;
        }
    }
}

// ---------------- FUSED layer 1 v5: LDS edge staging ----------------
// grid (1250, 2). Per rel phase: stage srcs/weights -> stage x-rows (all loads
// independent & coalesced) -> accumulate from LDS -> MFMA. Caps + global fallback.
#define PADK1 408
#define PADX1 136  // 128 + 8: rotates bank start by 4 dwords per slot
__global__ __launch_bounds__(256) void k_fused1(const int* __restrict__ keyoff, const int* __restrict__ srcs,
                                                const float* __restrict__ wcsr, const ushort_t* __restrict__ x,
                                                const ushort_t* __restrict__ wagg, float* __restrict__ part) {
    __shared__ int koffs[129];
    __shared__ int sbase[17];
    __shared__ int esrc[ECAP];
    __shared__ float wl[ECAP][3];
    __shared__ ushort_t xstage[RCAP][PADX1];  // 21.25 KB
    __shared__ ushort_t lt[16][PADK1];        // 12.75 KB
    const int tid = threadIdx.x;
    const int w = tid >> 6, lane = tid & 63;
    const int q15 = lane & 15, kq = (lane >> 4) * 8;
    const int l15 = lane & 15;
    const int nbase = blockIdx.x * 16;
    const int RB = blockIdx.y * 4;
    const int mynode = w * 4 + (lane >> 4);
    const int tn = tid >> 4, tj = tid & 15;

    if (tid < 129) koffs[tid] = keyoff[nbase * 8 + tid];
    __syncthreads();

    f32x4 acc = {};
    for (int rs = 0; rs < 4; rs++) {
        const int r = RB + rs;
        if (tid <= 16) {
            int run = 0;
            for (int m = 0; m < tid; m++) run += koffs[m * 8 + r + 1] - koffs[m * 8 + r];
            sbase[tid] = run;
        }
        __syncthreads();
        // stage srcs + weights (coalesced, independent)
        {
            int sb = sbase[tn];
            int gb = koffs[tn * 8 + r];
            int deg = koffs[tn * 8 + r + 1] - gb;
            for (int j = tj; j < deg; j += 16) {
                int slot = sb + j;
                if (slot < ECAP) {
                    esrc[slot] = srcs[gb + j];
                    wl[slot][0] = wcsr[(size_t)(gb + j) * 3 + 0];
                    wl[slot][1] = wcsr[(size_t)(gb + j) * 3 + 1];
                    wl[slot][2] = wcsr[(size_t)(gb + j) * 3 + 2];
                }
            }
        }
        __syncthreads();
        // stage x rows: 16 threads x 16B per row, all independent
        {
            int ns = sbase[16];
            int cap = ns < RCAP ? ns : RCAP;
            for (int s = tid >> 4; s < cap; s += 16)
                *(ushort8_t*)&xstage[s][tj * 8] = *(const ushort8_t*)&x[(size_t)esrc[s] * 128 + tj * 8];
        }
        __syncthreads();
        // accumulate from LDS (fallback to global past caps)
        {
            int sb = sbase[mynode];
            int deg = sbase[mynode + 1] - sb;
            int gb = koffs[mynode * 8 + r];
            float a0[8] = {}, a1[8] = {}, a2[8] = {};
            for (int j = 0; j < deg; j++) {
                int slot = sb + j;
                float w0, w1, w2;
                ushort8_t xv;
                if (slot < ECAP) {
                    w0 = wl[slot][0]; w1 = wl[slot][1]; w2 = wl[slot][2];
                } else {
                    w0 = wcsr[(size_t)(gb + j) * 3 + 0];
                    w1 = wcsr[(size_t)(gb + j) * 3 + 1];
                    w2 = wcsr[(size_t)(gb + j) * 3 + 2];
                }
                if (slot < RCAP) {
                    xv = *(const ushort8_t*)&xstage[slot][q15 * 8];
                } else {
                    int sv = (slot < ECAP) ? esrc[slot] : srcs[gb + j];
                    xv = *(const ushort8_t*)&x[(size_t)sv * 128 + q15 * 8];
                }
#pragma unroll
                for (int c = 0; c < 8; c++) {
                    float f = b2f(xv[c]);
                    a0[c] += w0 * f;
                    a1[c] += w1 * f;
                    a2[c] += w2 * f;
                }
            }
            ushort8_t o0, o1, o2;
#pragma unroll
            for (int c = 0; c < 8; c++) {
                o0[c] = f2b(a0[c]);
                o1[c] = f2b(a1[c]);
                o2[c] = f2b(a2[c]);
            }
            *(ushort8_t*)&lt[mynode][0 * 128 + q15 * 8] = o0;
            *(ushort8_t*)&lt[mynode][1 * 128 + q15 * 8] = o1;
            *(ushort8_t*)&lt[mynode][2 * 128 + q15 * 8] = o2;
        }
        __syncthreads();
#pragma unroll
        for (int ks = 0; ks < 12; ks++) {
            bf16x8 av = *(const bf16x8*)&lt[l15][ks * 32 + kq];
            bf16x8 bv = *(const bf16x8*)&wagg[(size_t)(w * 16 + l15) * 3072 + r * 384 + ks * 32 + kq];
            acc = __builtin_amdgcn_mfma_f32_16x16x32_bf16(av, bv, acc, 0, 0, 0);
        }
        __syncthreads();
    }
    float* op = part + (size_t)blockIdx.y * N_NODES * 64;
    const int r4 = (lane >> 4) * 4;
#pragma unroll
    for (int g = 0; g < 4; g++) {
        int row = nbase + r4 + g;
        op[(size_t)row * 64 + w * 16 + l15] = acc[g];
    }
}

// ---------------- FUSED layer 2 v5: LDS edge staging, redundant small MFMA ----------------
#define PADK2 208
#define PADX2 72  // 64 + 8
__global__ __launch_bounds__(256) void k_fused2(const int* __restrict__ keyoff, const int* __restrict__ srcs,
                                                const float* __restrict__ wcsr, const ushort_t* __restrict__ x2in,
                                                const ushort_t* __restrict__ wagg, float* __restrict__ part) {
    __shared__ int koffs[129];
    __shared__ int sbase[17];
    __shared__ int esrc[ECAP];
    __shared__ float wl[ECAP][3];
    __shared__ ushort_t xstage[RCAP][PADX2];  // 11.25 KB
    __shared__ ushort_t lt[16][PADK2];        // 6.5 KB
    const int tid = threadIdx.x;
    const int w = tid >> 6, lane = tid & 63;
    const int q15 = lane & 15, kq = (lane >> 4) * 8;
    const int l15 = lane & 15;
    const int nbase = blockIdx.x * 16;
    const int RB = blockIdx.y * 4;
    const int mynode = w * 4 + (lane >> 4);
    const int tn = tid >> 4, tj = tid & 15;

    if (tid < 129) koffs[tid] = keyoff[nbase * 8 + tid];
    __syncthreads();

    f32x4 acc = {};
    for (int rs = 0; rs < 4; rs++) {
        const int r = RB + rs;
        if (tid <= 16) {
            int run = 0;
            for (int m = 0; m < tid; m++) run += koffs[m * 8 + r + 1] - koffs[m * 8 + r];
            sbase[tid] = run;
        }
        __syncthreads();
        {
            int sb = sbase[tn];
            int gb = koffs[tn * 8 + r];
            int deg = koffs[tn * 8 + r + 1] - gb;
            for (int j = tj; j < deg; j += 16) {
                int slot = sb + j;
                if (slot < ECAP) {
                    esrc[slot] = srcs[gb + j];
                    wl[slot][0] = wcsr[(size_t)(gb + j) * 3 + 0];
                    wl[slot][1] = wcsr[(size_t)(gb + j) * 3 + 1];
                    wl[slot][2] = wcsr[(size_t)(gb + j) * 3 + 2];
                }
            }
        }
        __syncthreads();
        {
            int ns = sbase[16];
            int cap = ns < RCAP ? ns : RCAP;
            for (int s = tid >> 4; s < cap; s += 16)
                *(ushort4_t*)&xstage[s][tj * 4] = *(const ushort4_t*)&x2in[(size_t)esrc[s] * 64 + tj * 4];
        }
        __syncthreads();
        {
            int sb = sbase[mynode];
            int deg = sbase[mynode + 1] - sb;
            int gb = koffs[mynode * 8 + r];
            float a0[4] = {}, a1[4] = {}, a2[4] = {};
            for (int j = 0; j < deg; j++) {
                int slot = sb + j;
                float w0, w1, w2;
                ushort4_t xv;
                if (slot < ECAP) {
                    w0 = wl[slot][0]; w1 = wl[slot][1]; w2 = wl[slot][2];
                } else {
                    w0 = wcsr[(size_t)(gb + j) * 3 + 0];
                    w1 = wcsr[(size_t)(gb + j) * 3 + 1];
                    w2 = wcsr[(size_t)(gb + j) * 3 + 2];
                }
                if (slot < RCAP) {
                    xv = *(const ushort4_t*)&xstage[slot][q15 * 4];
                } else {
                    int sv = (slot < ECAP) ? esrc[slot] : srcs[gb + j];
                    xv = *(const ushort4_t*)&x2in[(size_t)sv * 64 + q15 * 4];
                }
#pragma unroll
                for (int c = 0; c < 4; c++) {
                    float f = b2f(xv[c]);
                    a0[c] += w0 * f;
                    a1[c] += w1 * f;
                    a2[c] += w2 * f;
                }
            }
            ushort4_t o0, o1, o2;
#pragma unroll
            for (int c = 0; c < 4; c++) {
                o0[c] = f2b(a0[c]);
                o1[c] = f2b(a1[c]);
                o2[c] = f2b(a2[c]);
            }
            *(ushort4_t*)&lt[mynode][0 * 64 + q15 * 4] = o0;
            *(ushort4_t*)&lt[mynode][1 * 64 + q15 * 4] = o1;
            *(ushort4_t*)&lt[mynode][2 * 64 + q15 * 4] = o2;
        }
        __syncthreads();
        // small MFMA (N=16, K=192): every wave computes it (redundant, removes reduce)
#pragma unroll
        for (int ks = 0; ks < 6; ks++) {
            bf16x8 av = *(const bf16x8*)&lt[l15][ks * 32 + kq];
            bf16x8 bv = *(const bf16x8*)&wagg[(size_t)l15 * 1536 + r * 192 + ks * 32 + kq];
            acc = __builtin_amdgcn_mfma_f32_16x16x32_bf16(av, bv, acc, 0, 0, 0);
        }
        __syncthreads();
    }
    if (w == 0) {
        const int r4 = (lane >> 4) * 4;
#pragma unroll
        for (int g = 0; g < 4; g++)
            part[(size_t)blockIdx.y * N_NODES * 16 + (size_t)(nbase + r4 + g) * 16 + l15] = acc[g];
    }
}

// ---------------- partials reduce + bias + relu -> bf16 x2 ----------------
__global__ __launch_bounds__(256) void k_reduce1(const float* __restrict__ part, const float* __restrict__ bias,
                                                 ushort_t* __restrict__ x2) {
    int idx = blockIdx.x * blockDim.x + threadIdx.x;
    const int MN = N_NODES * 64;
    if (idx >= MN) return;
    float s = part[idx] + part[idx + MN] + bias[idx & 63];
    x2[idx] = f2b(s > 0.f ? s : 0.f);
}

// ---------------- partials reduce + bias + sigmoid -> out f32 ----------------
__global__ __launch_bounds__(256) void k_reduce2(const float* __restrict__ part, const float* __restrict__ bias,
                                                 float* __restrict__ outp) {
    int idx = blockIdx.x * blockDim.x + threadIdx.x;
    const int MN = N_NODES * 16;
    if (idx >= MN) return;
    float s = part[idx] + part[idx + MN] + bias[idx & 15];
    outp[idx] = 1.f / (1.f + expf(-s));
}

extern "C" void kernel_launch(void* const* d_in, const int* in_sizes, int n_in, void* d_out, int out_size,
                              void* d_ws, size_t ws_size, hipStream_t stream) {
    const float* emb = (const float*)d_in[0];
    const float* w1 = (const float*)d_in[1];
    const float* q1 = (const float*)d_in[2];
    const float* k1 = (const float*)d_in[3];
    const float* b1 = (const float*)d_in[4];
    const float* w2 = (const float*)d_in[5];
    const float* q2 = (const float*)d_in[6];
    const float* k2 = (const float*)d_in[7];
    const float* b2 = (const float*)d_in[8];
    const int* eidx = (const int*)d_in[9];
    const int* etype = (const int*)d_in[10];
    const int* srcv = eidx;
    const int* dstv = eidx + N_EDGES;
    float* out = (float*)d_out;

    char* p = (char*)d_ws;
    auto alloc = [&](size_t bytes) -> void* {
        void* q = p;
        p += (bytes + 255) & ~(size_t)255;
        return q;
    };
    int* counts = (int*)alloc((size_t)NKEYS * 4);
    int* keyoff = (int*)alloc((size_t)(NKEYS + 1) * 4);
    int* cursor = (int*)alloc((size_t)NKEYS * 4);
    int* blocksum = (int*)alloc((size_t)SCAN_NBLK * 4);
    int* blockbase = (int*)alloc((size_t)SCAN_NBLK * 4);
    int* srcs = (int*)alloc((size_t)N_EDGES * 4);
    ushort_t* emb_b = (ushort_t*)alloc((size_t)N_NODES * EMB * 2);
    ushort_t* wqkt1 = (ushort_t*)alloc((size_t)48 * 128 * 2);
    ushort_t* wagg1 = (ushort_t*)alloc((size_t)64 * 3072 * 2);
    ushort_t* wqkt2 = (ushort_t*)alloc((size_t)48 * 64 * 2);
    ushort_t* wagg2 = (ushort_t*)alloc((size_t)16 * 1536 * 2);
    float* qkd = (float*)alloc((size_t)N_NODES * 48 * 4);
    float* wcsr = (float*)alloc((size_t)N_EDGES * 3 * 4);
    ushort_t* x2 = (ushort_t*)alloc((size_t)N_NODES * 64 * 2);
    float* partials = (float*)alloc((size_t)2 * N_NODES * 64 * 4);

    // ---- precomputes ----
    k_cvt<<<(N_NODES * EMB / 4 + 255) / 256, 256, 0, stream>>>(emb, emb_b, N_NODES * EMB / 4);
    k_wqk<128, 192><<<(48 * 128 + 255) / 256, 256, 0, stream>>>(w1, q1, k1, wqkt1);
    k_wqk<64, 48><<<(48 * 64 + 255) / 256, 256, 0, stream>>>(w2, q2, k2, wqkt2);
    k_wagg<128, 64><<<(64 * 3072 + 255) / 256, 256, 0, stream>>>(w1, wagg1);
    k_wagg<64, 16><<<(16 * 1536 + 255) / 256, 256, 0, stream>>>(w2, wagg2);

    // ---- CSR over (dst, rel) ----
    hipMemsetAsync(counts, 0, (size_t)NKEYS * 4, stream);
    k_count<<<(N_EDGES + 255) / 256, 256, 0, stream>>>(dstv, etype, counts);
    k_scanA<<<SCAN_NBLK, 256, 0, stream>>>(counts, keyoff, blocksum);
    k_scanB<<<1, 256, 0, stream>>>(blocksum, blockbase, keyoff);
    k_scanC<<<SCAN_NBLK, 256, 0, stream>>>(blockbase, keyoff, cursor);
    k_scatter<<<(N_EDGES + 255) / 256, 256, 0, stream>>>(srcv, dstv, etype, cursor, srcs);

    // ---- layer 1 ----
    k_mfma_gemm<128, 128, 48, 1, 3><<<dim3(313, 1), 256, 0, stream>>>(emb_b, wqkt1, qkd, N_NODES);
    k_stats<<<N_NODES / 4, 256, 0, stream>>>(keyoff, srcs, qkd, wcsr);
    k_fused1<<<dim3(N_NODES / 16, 2), 256, 0, stream>>>(keyoff, srcs, wcsr, emb_b, wagg1, partials);
    k_reduce1<<<(N_NODES * 64 + 255) / 256, 256, 0, stream>>>(partials, b1, x2);

    // ---- layer 2 ----
    k_mfma_gemm<64, 64, 48, 1, 3><<<dim3(313, 1), 256, 0, stream>>>(x2, wqkt2, qkd, N_NODES);
    k_stats<<<N_NODES / 4, 256, 0, stream>>>(keyoff, srcs, qkd, wcsr);
    k_fused2<<<dim3(N_NODES / 16, 2), 256, 0, stream>>>(keyoff, srcs, wcsr, x2, wagg2, partials);
    k_reduce2<<<(N_NODES * 16 + 255) / 256, 256, 0, stream>>>(partials, b2, out);
}

// Round 10
// 262.407 us; speedup vs baseline: 1.1919x; 1.1919x over previous
//
#include <hip/hip_runtime.h>
#include <hip/hip_bf16.h>
#include <math.h>

#define N_NODES 20000
#define EMB 128
#define HID 64
#define RELS 8
#define CLS 16
#define N_EDGES 640000
#define NEG 0.2f
#define NKEYS (N_NODES * RELS)
#define SCAN_CHUNK 1024
#define SCAN_NBLK ((NKEYS + SCAN_CHUNK - 1) / SCAN_CHUNK)  // 157

typedef unsigned short ushort_t;
typedef __attribute__((ext_vector_type(8))) short bf16x8;
typedef __attribute__((ext_vector_type(8))) unsigned short ushort8_t;
typedef __attribute__((ext_vector_type(4))) unsigned short ushort4_t;
typedef __attribute__((ext_vector_type(4))) float f32x4;

__device__ __forceinline__ float b2f(ushort_t u) {
    return __uint_as_float(((unsigned int)u) << 16);
}
__device__ __forceinline__ ushort_t f2b(float f) {
    __hip_bfloat16 h = __float2bfloat16(f);
    return *reinterpret_cast<ushort_t*>(&h);
}

// ---------------- f32 -> bf16 conversion ----------------
__global__ __launch_bounds__(256) void k_cvt(const float* __restrict__ in, ushort_t* __restrict__ outp, int n4) {
    int i = blockIdx.x * blockDim.x + threadIdx.x;
    if (i >= n4) return;
    float4 v = *(const float4*)&in[(size_t)i * 4];
    ushort4 o;
    o.x = f2b(v.x); o.y = f2b(v.y); o.z = f2b(v.z); o.w = f2b(v.w);
    *(ushort4*)&outp[(size_t)i * 4] = o;
}

// ---------------- Wqk precompute ----------------
template <int D, int OUT>
__global__ __launch_bounds__(256) void k_wqk(const float* __restrict__ w, const float* __restrict__ q,
                                             const float* __restrict__ k, ushort_t* __restrict__ wqkt) {
    int tid = blockIdx.x * blockDim.x + threadIdx.x;
    if (tid >= 48 * D) return;
    int c = tid / D, i = tid % D;
    int r = c / 6, j = c % 6;
    const float* qk = (j < 3) ? q : k;
    int jj = (j < 3) ? j : j - 3;
    const float* wrow = w + ((size_t)r * D + i) * OUT;
    float s = 0.f;
    for (int o = 0; o < OUT; o++) s += wrow[o] * qk[o * 3 + jj];
    wqkt[(size_t)c * D + i] = f2b(s);
}

// ---------------- Wagg precompute: Bt[o][(r*3+h)*D + i] = w[r][i][h*OC + o] ----------------
template <int D, int OC>
__global__ __launch_bounds__(256) void k_wagg(const float* __restrict__ w, ushort_t* __restrict__ outp) {
    const int KT = RELS * 3 * D;
    int tid = blockIdx.x * blockDim.x + threadIdx.x;
    if (tid >= OC * KT) return;
    int o = tid / KT, kidx = tid % KT;
    int r = kidx / (3 * D), h = (kidx / D) % 3, i = kidx % D;
    float v = w[((size_t)r * D + i) * (3 * OC) + h * OC + o];
    outp[tid] = f2b(v);
}

// ---------------- CSR build over keys = dst*8 + rel ----------------
__global__ __launch_bounds__(256) void k_count(const int* __restrict__ dst, const int* __restrict__ et,
                                               int* __restrict__ counts) {
    int e = blockIdx.x * blockDim.x + threadIdx.x;
    if (e < N_EDGES) atomicAdd(&counts[dst[e] * 8 + et[e]], 1);
}

__global__ __launch_bounds__(256) void k_scanA(const int* __restrict__ counts, int* __restrict__ keyoff,
                                               int* __restrict__ blocksum) {
    __shared__ int part[256];
    int b = blockIdx.x, tid = threadIdx.x;
    int base = b * SCAN_CHUNK + tid * 4;
    int4 c = make_int4(0, 0, 0, 0);
    if (base + 3 < NKEYS) c = *(const int4*)&counts[base];
    else {
        if (base + 0 < NKEYS) c.x = counts[base + 0];
        if (base + 1 < NKEYS) c.y = counts[base + 1];
        if (base + 2 < NKEYS) c.z = counts[base + 2];
        if (base + 3 < NKEYS) c.w = counts[base + 3];
    }
    int s = c.x + c.y + c.z + c.w;
    part[tid] = s;
    __syncthreads();
    for (int off = 1; off < 256; off <<= 1) {
        int v = (tid >= off) ? part[tid - off] : 0;
        __syncthreads();
        part[tid] += v;
        __syncthreads();
    }
    int excl = part[tid] - s;
    int4 o;
    o.x = excl;
    o.y = excl + c.x;
    o.z = excl + c.x + c.y;
    o.w = excl + c.x + c.y + c.z;
    if (base + 3 < NKEYS) *(int4*)&keyoff[base] = o;
    else {
        if (base + 0 < NKEYS) keyoff[base + 0] = o.x;
        if (base + 1 < NKEYS) keyoff[base + 1] = o.y;
        if (base + 2 < NKEYS) keyoff[base + 2] = o.z;
        if (base + 3 < NKEYS) keyoff[base + 3] = o.w;
    }
    if (tid == 255) blocksum[b] = part[255];
}

__global__ __launch_bounds__(256) void k_scanB(int* __restrict__ blocksum, int* __restrict__ blockbase,
                                               int* __restrict__ keyoff) {
    __shared__ int part[256];
    int tid = threadIdx.x;
    int v0 = (tid < SCAN_NBLK) ? blocksum[tid] : 0;
    part[tid] = v0;
    __syncthreads();
    for (int off = 1; off < 256; off <<= 1) {
        int v = (tid >= off) ? part[tid - off] : 0;
        __syncthreads();
        part[tid] += v;
        __syncthreads();
    }
    if (tid < SCAN_NBLK) blockbase[tid] = part[tid] - v0;
    if (tid == 255) keyoff[NKEYS] = part[255];
}

__global__ __launch_bounds__(256) void k_scanC(const int* __restrict__ blockbase, int* __restrict__ keyoff,
                                               int* __restrict__ cursor) {
    int b = blockIdx.x, tid = threadIdx.x;
    int base = b * SCAN_CHUNK + tid * 4;
    int add = blockbase[b];
    if (base + 3 < NKEYS) {
        int4 v = *(const int4*)&keyoff[base];
        v.x += add; v.y += add; v.z += add; v.w += add;
        *(int4*)&keyoff[base] = v;
        *(int4*)&cursor[base] = v;
    } else {
        for (int j = 0; j < 4; j++) {
            if (base + j < NKEYS) {
                int v = keyoff[base + j] + add;
                keyoff[base + j] = v;
                cursor[base + j] = v;
            }
        }
    }
}

// ---------------- scatter srcs into CSR order ----------------
__global__ __launch_bounds__(256) void k_scatter(const int* __restrict__ src, const int* __restrict__ dst,
                                                 const int* __restrict__ et, int* __restrict__ cursor,
                                                 int* __restrict__ srcs) {
    int e = blockIdx.x * blockDim.x + threadIdx.x;
    if (e < N_EDGES) {
        int p = atomicAdd(&cursor[dst[e] * 8 + et[e]], 1);
        srcs[p] = src[e];
    }
}

// ---------------- direct-fragment MFMA GEMM (qkd projections) ----------------
template <int K, int KCH, int N, int MREP, int NREP>
__global__ __launch_bounds__(256) void k_mfma_gemm(const ushort_t* __restrict__ A, const ushort_t* __restrict__ Bt,
                                                   float* __restrict__ outp, int M) {
    const int wid = threadIdx.x >> 6;
    const int lane = threadIdx.x & 63;
    const int m0 = blockIdx.x * (4 * MREP * 16) + wid * (MREP * 16);
    const int kbase = blockIdx.y * KCH;
    const int l15 = lane & 15;
    const int kq = (lane >> 4) * 8;

    f32x4 acc[MREP][NREP] = {};
    for (int kk = kbase; kk < kbase + KCH; kk += 32) {
        bf16x8 a[MREP], b[NREP];
#pragma unroll
        for (int i = 0; i < MREP; i++) {
            int row = m0 + i * 16 + l15;
            row = row < M ? row : M - 1;
            a[i] = *(const bf16x8*)&A[(size_t)row * K + kk + kq];
        }
#pragma unroll
        for (int j = 0; j < NREP; j++) b[j] = *(const bf16x8*)&Bt[(size_t)(j * 16 + l15) * K + kk + kq];
#pragma unroll
        for (int i = 0; i < MREP; i++)
#pragma unroll
            for (int j = 0; j < NREP; j++)
                acc[i][j] = __builtin_amdgcn_mfma_f32_16x16x32_bf16(a[i], b[j], acc[i][j], 0, 0, 0);
    }
    float* op = outp + (size_t)blockIdx.y * M * N;
    const int r4 = (lane >> 4) * 4;
#pragma unroll
    for (int i = 0; i < MREP; i++) {
#pragma unroll
        for (int j = 0; j < NREP; j++) {
#pragma unroll
            for (int g = 0; g < 4; g++) {
                int row = m0 + i * 16 + r4 + g;
                if (row < M) op[(size_t)row * N + j * 16 + l15] = acc[i][j][g];
            }
        }
    }
}

// ---------------- per-edge alpha from qkd (on the fly), also returns src ----------------
__device__ __forceinline__ void edge_alpha(int s_idx, const int (&ko)[9], const int* __restrict__ srcs,
                                           const float* __restrict__ qkd, const float* __restrict__ qbase,
                                           float& a0, float& a1, float& a2, int& sv) {
    int r = 0;
#pragma unroll
    for (int j = 1; j < 8; j++) r += (s_idx >= ko[j]) ? 1 : 0;
    sv = srcs[s_idx];
    const float* kd = qkd + (size_t)sv * 48 + r * 6 + 3;
    const float* qd = qbase + r * 6;
    float t0 = qd[0] + kd[0], t1 = qd[1] + kd[1], t2 = qd[2] + kd[2];
    a0 = t0 > 0.f ? t0 : NEG * t0;
    a1 = t1 > 0.f ? t1 : NEG * t1;
    a2 = t2 > 0.f ? t2 : NEG * t2;
}

// ---------------- softmax stats -> svw[e] = {src_bits, w0, w1, w2} ----------------
__global__ __launch_bounds__(256) void k_stats(const int* __restrict__ keyoff, const int* __restrict__ srcs,
                                               const float* __restrict__ qkd, float4* __restrict__ svw) {
    int node = blockIdx.x * 4 + (threadIdx.x >> 6);
    int lane = threadIdx.x & 63;
    int ko[9];
#pragma unroll
    for (int j = 0; j < 9; j++) ko[j] = keyoff[node * 8 + j];
    int beg = ko[0], end = ko[8], deg = end - beg;
    if (deg == 0) return;
    const float* qbase = qkd + (size_t)node * 48;

    if (deg <= 64) {
        float a0 = -INFINITY, a1 = -INFINITY, a2 = -INFINITY;
        int sv = 0;
        if (lane < deg) edge_alpha(beg + lane, ko, srcs, qkd, qbase, a0, a1, a2, sv);
        float m0 = a0, m1 = a1, m2 = a2;
#pragma unroll
        for (int off = 32; off >= 1; off >>= 1) {
            m0 = fmaxf(m0, __shfl_xor(m0, off));
            m1 = fmaxf(m1, __shfl_xor(m1, off));
            m2 = fmaxf(m2, __shfl_xor(m2, off));
        }
        float e0 = 0.f, e1 = 0.f, e2 = 0.f;
        if (lane < deg) {
            e0 = expf(a0 - m0);
            e1 = expf(a1 - m1);
            e2 = expf(a2 - m2);
        }
        float s0 = e0, s1 = e1, s2 = e2;
#pragma unroll
        for (int off = 32; off >= 1; off >>= 1) {
            s0 += __shfl_xor(s0, off);
            s1 += __shfl_xor(s1, off);
            s2 += __shfl_xor(s2, off);
        }
        float i0 = 1.f / (3.f * (s0 + 1e-16f));
        float i1 = 1.f / (3.f * (s1 + 1e-16f));
        float i2 = 1.f / (3.f * (s2 + 1e-16f));
        if (lane < deg)
            svw[beg + lane] = make_float4(__int_as_float(sv), e0 * i0, e1 * i1, e2 * i2);
    } else {
        float m0 = -INFINITY, m1 = -INFINITY, m2 = -INFINITY;
        for (int i = beg + lane; i < end; i += 64) {
            float a0, a1, a2; int sv;
            edge_alpha(i, ko, srcs, qkd, qbase, a0, a1, a2, sv);
            m0 = fmaxf(m0, a0); m1 = fmaxf(m1, a1); m2 = fmaxf(m2, a2);
        }
#pragma unroll
        for (int off = 32; off >= 1; off >>= 1) {
            m0 = fmaxf(m0, __shfl_xor(m0, off));
            m1 = fmaxf(m1, __shfl_xor(m1, off));
            m2 = fmaxf(m2, __shfl_xor(m2, off));
        }
        float s0 = 0.f, s1 = 0.f, s2 = 0.f;
        for (int i = beg + lane; i < end; i += 64) {
            float a0, a1, a2; int sv;
            edge_alpha(i, ko, srcs, qkd, qbase, a0, a1, a2, sv);
            s0 += expf(a0 - m0); s1 += expf(a1 - m1); s2 += expf(a2 - m2);
        }
#pragma unroll
        for (int off = 32; off >= 1; off >>= 1) {
            s0 += __shfl_xor(s0, off);
            s1 += __shfl_xor(s1, off);
            s2 += __shfl_xor(s2, off);
        }
        float i0 = 1.f / (3.f * (s0 + 1e-16f));
        float i1 = 1.f / (3.f * (s1 + 1e-16f));
        float i2 = 1.f / (3.f * (s2 + 1e-16f));
        for (int i = beg + lane; i < end; i += 64) {
            float a0, a1, a2; int sv;
            edge_alpha(i, ko, srcs, qkd, qbase, a0, a1, a2, sv);
            svw[i] = make_float4(__int_as_float(sv), expf(a0 - m0) * i0, expf(a1 - m1) * i1, expf(a2 - m2) * i2);
        }
    }
}

// ---------------- FUSED layer 1 v6: one rel per block, one barrier, max TLP ----------------
// grid (1250, 8). 16 nodes/block, quarter-wave per node. svw = 1 load/edge.
#define PADK1 408
__global__ __launch_bounds__(256) void k_fused1(const int* __restrict__ keyoff, const float4* __restrict__ svw,
                                                const ushort_t* __restrict__ x, const ushort_t* __restrict__ wagg,
                                                float* __restrict__ part) {
    __shared__ ushort_t lt[16][PADK1];  // 12.75 KB (only LDS)
    const int tid = threadIdx.x;
    const int w = tid >> 6, lane = tid & 63;
    const int q15 = lane & 15, kq = (lane >> 4) * 8;
    const int l15 = lane & 15;
    const int nbase = blockIdx.x * 16;
    const int r = blockIdx.y;
    const int mynode = w * 4 + (lane >> 4);
    const int key = (nbase + mynode) * 8 + r;

    const int beg = keyoff[key], end = keyoff[key + 1];
    float a0[8] = {}, a1[8] = {}, a2[8] = {};
    for (int s = beg; s < end; s++) {
        float4 sw = svw[s];  // sequential address: pipelines
        int sv = __float_as_int(sw.x);
        ushort8_t xv = *(const ushort8_t*)&x[(size_t)sv * 128 + q15 * 8];
#pragma unroll
        for (int c = 0; c < 8; c++) {
            float f = b2f(xv[c]);
            a0[c] += sw.y * f;
            a1[c] += sw.z * f;
            a2[c] += sw.w * f;
        }
    }
    ushort8_t o0, o1, o2;
#pragma unroll
    for (int c = 0; c < 8; c++) {
        o0[c] = f2b(a0[c]);
        o1[c] = f2b(a1[c]);
        o2[c] = f2b(a2[c]);
    }
    *(ushort8_t*)&lt[mynode][0 * 128 + q15 * 8] = o0;
    *(ushort8_t*)&lt[mynode][1 * 128 + q15 * 8] = o1;
    *(ushort8_t*)&lt[mynode][2 * 128 + q15 * 8] = o2;
    __syncthreads();

    f32x4 acc = {};
#pragma unroll
    for (int ks = 0; ks < 12; ks++) {
        bf16x8 av = *(const bf16x8*)&lt[l15][ks * 32 + kq];
        bf16x8 bv = *(const bf16x8*)&wagg[(size_t)(w * 16 + l15) * 3072 + r * 384 + ks * 32 + kq];
        acc = __builtin_amdgcn_mfma_f32_16x16x32_bf16(av, bv, acc, 0, 0, 0);
    }
    float* op = part + (size_t)r * N_NODES * 64;
    const int r4 = (lane >> 4) * 4;
#pragma unroll
    for (int g = 0; g < 4; g++) {
        int row = nbase + r4 + g;
        op[(size_t)row * 64 + w * 16 + l15] = acc[g];
    }
}

// ---------------- FUSED layer 2 v6: one rel per block ----------------
#define PADK2 208
__global__ __launch_bounds__(256) void k_fused2(const int* __restrict__ keyoff, const float4* __restrict__ svw,
                                                const ushort_t* __restrict__ x2in, const ushort_t* __restrict__ wagg,
                                                float* __restrict__ part) {
    __shared__ ushort_t lt[16][PADK2];  // 6.5 KB
    const int tid = threadIdx.x;
    const int w = tid >> 6, lane = tid & 63;
    const int q15 = lane & 15, kq = (lane >> 4) * 8;
    const int l15 = lane & 15;
    const int nbase = blockIdx.x * 16;
    const int r = blockIdx.y;
    const int mynode = w * 4 + (lane >> 4);
    const int key = (nbase + mynode) * 8 + r;

    const int beg = keyoff[key], end = keyoff[key + 1];
    float a0[4] = {}, a1[4] = {}, a2[4] = {};
    for (int s = beg; s < end; s++) {
        float4 sw = svw[s];
        int sv = __float_as_int(sw.x);
        ushort4_t xv = *(const ushort4_t*)&x2in[(size_t)sv * 64 + q15 * 4];
#pragma unroll
        for (int c = 0; c < 4; c++) {
            float f = b2f(xv[c]);
            a0[c] += sw.y * f;
            a1[c] += sw.z * f;
            a2[c] += sw.w * f;
        }
    }
    ushort4_t o0, o1, o2;
#pragma unroll
    for (int c = 0; c < 4; c++) {
        o0[c] = f2b(a0[c]);
        o1[c] = f2b(a1[c]);
        o2[c] = f2b(a2[c]);
    }
    *(ushort4_t*)&lt[mynode][0 * 64 + q15 * 4] = o0;
    *(ushort4_t*)&lt[mynode][1 * 64 + q15 * 4] = o1;
    *(ushort4_t*)&lt[mynode][2 * 64 + q15 * 4] = o2;
    __syncthreads();

    if (w == 0) {
        f32x4 acc = {};
#pragma unroll
        for (int ks = 0; ks < 6; ks++) {
            bf16x8 av = *(const bf16x8*)&lt[l15][ks * 32 + kq];
            bf16x8 bv = *(const bf16x8*)&wagg[(size_t)l15 * 1536 + r * 192 + ks * 32 + kq];
            acc = __builtin_amdgcn_mfma_f32_16x16x32_bf16(av, bv, acc, 0, 0, 0);
        }
        const int r4 = (lane >> 4) * 4;
#pragma unroll
        for (int g = 0; g < 4; g++)
            part[(size_t)r * N_NODES * 16 + (size_t)(nbase + r4 + g) * 16 + l15] = acc[g];
    }
}

// ---------------- 8-way partials reduce + bias + relu -> bf16 x2 ----------------
__global__ __launch_bounds__(256) void k_reduce1(const float* __restrict__ part, const float* __restrict__ bias,
                                                 ushort_t* __restrict__ x2) {
    int idx = blockIdx.x * blockDim.x + threadIdx.x;
    const int MN = N_NODES * 64;
    if (idx >= MN) return;
    float s = bias[idx & 63];
#pragma unroll
    for (int r = 0; r < 8; r++) s += part[idx + (size_t)r * MN];
    x2[idx] = f2b(s > 0.f ? s : 0.f);
}

// ---------------- 8-way partials reduce + bias + sigmoid -> out f32 ----------------
__global__ __launch_bounds__(256) void k_reduce2(const float* __restrict__ part, const float* __restrict__ bias,
                                                 float* __restrict__ outp) {
    int idx = blockIdx.x * blockDim.x + threadIdx.x;
    const int MN = N_NODES * 16;
    if (idx >= MN) return;
    float s = bias[idx & 15];
#pragma unroll
    for (int r = 0; r < 8; r++) s += part[idx + (size_t)r * MN];
    outp[idx] = 1.f / (1.f + expf(-s));
}

extern "C" void kernel_launch(void* const* d_in, const int* in_sizes, int n_in, void* d_out, int out_size,
                              void* d_ws, size_t ws_size, hipStream_t stream) {
    const float* emb = (const float*)d_in[0];
    const float* w1 = (const float*)d_in[1];
    const float* q1 = (const float*)d_in[2];
    const float* k1 = (const float*)d_in[3];
    const float* b1 = (const float*)d_in[4];
    const float* w2 = (const float*)d_in[5];
    const float* q2 = (const float*)d_in[6];
    const float* k2 = (const float*)d_in[7];
    const float* b2 = (const float*)d_in[8];
    const int* eidx = (const int*)d_in[9];
    const int* etype = (const int*)d_in[10];
    const int* srcv = eidx;
    const int* dstv = eidx + N_EDGES;
    float* out = (float*)d_out;

    char* p = (char*)d_ws;
    auto alloc = [&](size_t bytes) -> void* {
        void* q = p;
        p += (bytes + 255) & ~(size_t)255;
        return q;
    };
    int* counts = (int*)alloc((size_t)NKEYS * 4);
    int* keyoff = (int*)alloc((size_t)(NKEYS + 1) * 4);
    int* cursor = (int*)alloc((size_t)NKEYS * 4);
    int* blocksum = (int*)alloc((size_t)SCAN_NBLK * 4);
    int* blockbase = (int*)alloc((size_t)SCAN_NBLK * 4);
    int* srcs = (int*)alloc((size_t)N_EDGES * 4);
    float4* svw = (float4*)alloc((size_t)N_EDGES * 16);
    ushort_t* emb_b = (ushort_t*)alloc((size_t)N_NODES * EMB * 2);
    ushort_t* wqkt1 = (ushort_t*)alloc((size_t)48 * 128 * 2);
    ushort_t* wagg1 = (ushort_t*)alloc((size_t)64 * 3072 * 2);
    ushort_t* wqkt2 = (ushort_t*)alloc((size_t)48 * 64 * 2);
    ushort_t* wagg2 = (ushort_t*)alloc((size_t)16 * 1536 * 2);
    float* qkd = (float*)alloc((size_t)N_NODES * 48 * 4);
    ushort_t* x2 = (ushort_t*)alloc((size_t)N_NODES * 64 * 2);
    float* partials = (float*)alloc((size_t)8 * N_NODES * 64 * 4);

    // ---- precomputes ----
    k_cvt<<<(N_NODES * EMB / 4 + 255) / 256, 256, 0, stream>>>(emb, emb_b, N_NODES * EMB / 4);
    k_wqk<128, 192><<<(48 * 128 + 255) / 256, 256, 0, stream>>>(w1, q1, k1, wqkt1);
    k_wqk<64, 48><<<(48 * 64 + 255) / 256, 256, 0, stream>>>(w2, q2, k2, wqkt2);
    k_wagg<128, 64><<<(64 * 3072 + 255) / 256, 256, 0, stream>>>(w1, wagg1);
    k_wagg<64, 16><<<(16 * 1536 + 255) / 256, 256, 0, stream>>>(w2, wagg2);

    // ---- CSR over (dst, rel) ----
    hipMemsetAsync(counts, 0, (size_t)NKEYS * 4, stream);
    k_count<<<(N_EDGES + 255) / 256, 256, 0, stream>>>(dstv, etype, counts);
    k_scanA<<<SCAN_NBLK, 256, 0, stream>>>(counts, keyoff, blocksum);
    k_scanB<<<1, 256, 0, stream>>>(blocksum, blockbase, keyoff);
    k_scanC<<<SCAN_NBLK, 256, 0, stream>>>(blockbase, keyoff, cursor);
    k_scatter<<<(N_EDGES + 255) / 256, 256, 0, stream>>>(srcv, dstv, etype, cursor, srcs);

    // ---- layer 1 ----
    k_mfma_gemm<128, 128, 48, 1, 3><<<dim3(313, 1), 256, 0, stream>>>(emb_b, wqkt1, qkd, N_NODES);
    k_stats<<<N_NODES / 4, 256, 0, stream>>>(keyoff, srcs, qkd, svw);
    k_fused1<<<dim3(N_NODES / 16, 8), 256, 0, stream>>>(keyoff, svw, emb_b, wagg1, partials);
    k_reduce1<<<(N_NODES * 64 + 255) / 256, 256, 0, stream>>>(partials, b1, x2);

    // ---- layer 2 ----
    k_mfma_gemm<64, 64, 48, 1, 3><<<dim3(313, 1), 256, 0, stream>>>(x2, wqkt2, qkd, N_NODES);
    k_stats<<<N_NODES / 4, 256, 0, stream>>>(keyoff, srcs, qkd, svw);
    k_fused2<<<dim3(N_NODES / 16, 8), 256, 0, stream>>>(keyoff, svw, x2, wagg2, partials);
    k_reduce2<<<(N_NODES * 16 + 255) / 256, 256, 0, stream>>>(partials, b2, out);
}

// Round 11
// 256.343 us; speedup vs baseline: 1.2201x; 1.0237x over previous
//
#include <hip/hip_runtime.h>
#include <hip/hip_bf16.h>
#include <math.h>

#define N_NODES 20000
#define EMB 128
#define HID 64
#define RELS 8
#define CLS 16
#define N_EDGES 640000
#define NEG 0.2f
#define NKEYS (N_NODES * RELS)
#define SCAN_CHUNK 1024
#define SCAN_NBLK ((NKEYS + SCAN_CHUNK - 1) / SCAN_CHUNK)  // 157
#define BATCH 4

typedef unsigned short ushort_t;
typedef __attribute__((ext_vector_type(8))) short bf16x8;
typedef __attribute__((ext_vector_type(8))) unsigned short ushort8_t;
typedef __attribute__((ext_vector_type(4))) unsigned short ushort4_t;
typedef __attribute__((ext_vector_type(4))) float f32x4;

__device__ __forceinline__ float b2f(ushort_t u) {
    return __uint_as_float(((unsigned int)u) << 16);
}
__device__ __forceinline__ ushort_t f2b(float f) {
    __hip_bfloat16 h = __float2bfloat16(f);
    return *reinterpret_cast<ushort_t*>(&h);
}

// ---------------- f32 -> bf16 conversion ----------------
__global__ __launch_bounds__(256) void k_cvt(const float* __restrict__ in, ushort_t* __restrict__ outp, int n4) {
    int i = blockIdx.x * blockDim.x + threadIdx.x;
    if (i >= n4) return;
    float4 v = *(const float4*)&in[(size_t)i * 4];
    ushort4 o;
    o.x = f2b(v.x); o.y = f2b(v.y); o.z = f2b(v.z); o.w = f2b(v.w);
    *(ushort4*)&outp[(size_t)i * 4] = o;
}

// ---------------- Wqk precompute ----------------
template <int D, int OUT>
__global__ __launch_bounds__(256) void k_wqk(const float* __restrict__ w, const float* __restrict__ q,
                                             const float* __restrict__ k, ushort_t* __restrict__ wqkt) {
    int tid = blockIdx.x * blockDim.x + threadIdx.x;
    if (tid >= 48 * D) return;
    int c = tid / D, i = tid % D;
    int r = c / 6, j = c % 6;
    const float* qk = (j < 3) ? q : k;
    int jj = (j < 3) ? j : j - 3;
    const float* wrow = w + ((size_t)r * D + i) * OUT;
    float s = 0.f;
    for (int o = 0; o < OUT; o++) s += wrow[o] * qk[o * 3 + jj];
    wqkt[(size_t)c * D + i] = f2b(s);
}

// ---------------- Wagg precompute: Bt[o][(r*3+h)*D + i] = w[r][i][h*OC + o] ----------------
template <int D, int OC>
__global__ __launch_bounds__(256) void k_wagg(const float* __restrict__ w, ushort_t* __restrict__ outp) {
    const int KT = RELS * 3 * D;
    int tid = blockIdx.x * blockDim.x + threadIdx.x;
    if (tid >= OC * KT) return;
    int o = tid / KT, kidx = tid % KT;
    int r = kidx / (3 * D), h = (kidx / D) % 3, i = kidx % D;
    float v = w[((size_t)r * D + i) * (3 * OC) + h * OC + o];
    outp[tid] = f2b(v);
}

// ---------------- CSR build over keys = dst*8 + rel ----------------
__global__ __launch_bounds__(256) void k_count(const int* __restrict__ dst, const int* __restrict__ et,
                                               int* __restrict__ counts) {
    int e = blockIdx.x * blockDim.x + threadIdx.x;
    if (e < N_EDGES) atomicAdd(&counts[dst[e] * 8 + et[e]], 1);
}

__global__ __launch_bounds__(256) void k_scanA(const int* __restrict__ counts, int* __restrict__ keyoff,
                                               int* __restrict__ blocksum) {
    __shared__ int part[256];
    int b = blockIdx.x, tid = threadIdx.x;
    int base = b * SCAN_CHUNK + tid * 4;
    int4 c = make_int4(0, 0, 0, 0);
    if (base + 3 < NKEYS) c = *(const int4*)&counts[base];
    else {
        if (base + 0 < NKEYS) c.x = counts[base + 0];
        if (base + 1 < NKEYS) c.y = counts[base + 1];
        if (base + 2 < NKEYS) c.z = counts[base + 2];
        if (base + 3 < NKEYS) c.w = counts[base + 3];
    }
    int s = c.x + c.y + c.z + c.w;
    part[tid] = s;
    __syncthreads();
    for (int off = 1; off < 256; off <<= 1) {
        int v = (tid >= off) ? part[tid - off] : 0;
        __syncthreads();
        part[tid] += v;
        __syncthreads();
    }
    int excl = part[tid] - s;
    int4 o;
    o.x = excl;
    o.y = excl + c.x;
    o.z = excl + c.x + c.y;
    o.w = excl + c.x + c.y + c.z;
    if (base + 3 < NKEYS) *(int4*)&keyoff[base] = o;
    else {
        if (base + 0 < NKEYS) keyoff[base + 0] = o.x;
        if (base + 1 < NKEYS) keyoff[base + 1] = o.y;
        if (base + 2 < NKEYS) keyoff[base + 2] = o.z;
        if (base + 3 < NKEYS) keyoff[base + 3] = o.w;
    }
    if (tid == 255) blocksum[b] = part[255];
}

__global__ __launch_bounds__(256) void k_scanB(int* __restrict__ blocksum, int* __restrict__ blockbase,
                                               int* __restrict__ keyoff) {
    __shared__ int part[256];
    int tid = threadIdx.x;
    int v0 = (tid < SCAN_NBLK) ? blocksum[tid] : 0;
    part[tid] = v0;
    __syncthreads();
    for (int off = 1; off < 256; off <<= 1) {
        int v = (tid >= off) ? part[tid - off] : 0;
        __syncthreads();
        part[tid] += v;
        __syncthreads();
    }
    if (tid < SCAN_NBLK) blockbase[tid] = part[tid] - v0;
    if (tid == 255) keyoff[NKEYS] = part[255];
}

__global__ __launch_bounds__(256) void k_scanC(const int* __restrict__ blockbase, int* __restrict__ keyoff,
                                               int* __restrict__ cursor) {
    int b = blockIdx.x, tid = threadIdx.x;
    int base = b * SCAN_CHUNK + tid * 4;
    int add = blockbase[b];
    if (base + 3 < NKEYS) {
        int4 v = *(const int4*)&keyoff[base];
        v.x += add; v.y += add; v.z += add; v.w += add;
        *(int4*)&keyoff[base] = v;
        *(int4*)&cursor[base] = v;
    } else {
        for (int j = 0; j < 4; j++) {
            if (base + j < NKEYS) {
                int v = keyoff[base + j] + add;
                keyoff[base + j] = v;
                cursor[base + j] = v;
            }
        }
    }
}

// ---------------- scatter srcs into CSR order ----------------
__global__ __launch_bounds__(256) void k_scatter(const int* __restrict__ src, const int* __restrict__ dst,
                                                 const int* __restrict__ et, int* __restrict__ cursor,
                                                 int* __restrict__ srcs) {
    int e = blockIdx.x * blockDim.x + threadIdx.x;
    if (e < N_EDGES) {
        int p = atomicAdd(&cursor[dst[e] * 8 + et[e]], 1);
        srcs[p] = src[e];
    }
}

// ---------------- direct-fragment MFMA GEMM (qkd projections) ----------------
template <int K, int KCH, int N, int MREP, int NREP>
__global__ __launch_bounds__(256) void k_mfma_gemm(const ushort_t* __restrict__ A, const ushort_t* __restrict__ Bt,
                                                   float* __restrict__ outp, int M) {
    const int wid = threadIdx.x >> 6;
    const int lane = threadIdx.x & 63;
    const int m0 = blockIdx.x * (4 * MREP * 16) + wid * (MREP * 16);
    const int kbase = blockIdx.y * KCH;
    const int l15 = lane & 15;
    const int kq = (lane >> 4) * 8;

    f32x4 acc[MREP][NREP] = {};
    for (int kk = kbase; kk < kbase + KCH; kk += 32) {
        bf16x8 a[MREP], b[NREP];
#pragma unroll
        for (int i = 0; i < MREP; i++) {
            int row = m0 + i * 16 + l15;
            row = row < M ? row : M - 1;
            a[i] = *(const bf16x8*)&A[(size_t)row * K + kk + kq];
        }
#pragma unroll
        for (int j = 0; j < NREP; j++) b[j] = *(const bf16x8*)&Bt[(size_t)(j * 16 + l15) * K + kk + kq];
#pragma unroll
        for (int i = 0; i < MREP; i++)
#pragma unroll
            for (int j = 0; j < NREP; j++)
                acc[i][j] = __builtin_amdgcn_mfma_f32_16x16x32_bf16(a[i], b[j], acc[i][j], 0, 0, 0);
    }
    float* op = outp + (size_t)blockIdx.y * M * N;
    const int r4 = (lane >> 4) * 4;
#pragma unroll
    for (int i = 0; i < MREP; i++) {
#pragma unroll
        for (int j = 0; j < NREP; j++) {
#pragma unroll
            for (int g = 0; g < 4; g++) {
                int row = m0 + i * 16 + r4 + g;
                if (row < M) op[(size_t)row * N + j * 16 + l15] = acc[i][j][g];
            }
        }
    }
}

// ---------------- per-edge alpha from qkd (on the fly), also returns src ----------------
__device__ __forceinline__ void edge_alpha(int s_idx, const int (&ko)[9], const int* __restrict__ srcs,
                                           const float* __restrict__ qkd, const float* __restrict__ qbase,
                                           float& a0, float& a1, float& a2, int& sv) {
    int r = 0;
#pragma unroll
    for (int j = 1; j < 8; j++) r += (s_idx >= ko[j]) ? 1 : 0;
    sv = srcs[s_idx];
    const float* kd = qkd + (size_t)sv * 48 + r * 6 + 3;
    const float* qd = qbase + r * 6;
    float t0 = qd[0] + kd[0], t1 = qd[1] + kd[1], t2 = qd[2] + kd[2];
    a0 = t0 > 0.f ? t0 : NEG * t0;
    a1 = t1 > 0.f ? t1 : NEG * t1;
    a2 = t2 > 0.f ? t2 : NEG * t2;
}

// ---------------- softmax stats -> svw[e] = {src_bits, w0, w1, w2} ----------------
__global__ __launch_bounds__(256) void k_stats(const int* __restrict__ keyoff, const int* __restrict__ srcs,
                                               const float* __restrict__ qkd, float4* __restrict__ svw) {
    int node = blockIdx.x * 4 + (threadIdx.x >> 6);
    int lane = threadIdx.x & 63;
    int ko[9];
#pragma unroll
    for (int j = 0; j < 9; j++) ko[j] = keyoff[node * 8 + j];
    int beg = ko[0], end = ko[8], deg = end - beg;
    if (deg == 0) return;
    const float* qbase = qkd + (size_t)node * 48;

    if (deg <= 64) {
        float a0 = -INFINITY, a1 = -INFINITY, a2 = -INFINITY;
        int sv = 0;
        if (lane < deg) edge_alpha(beg + lane, ko, srcs, qkd, qbase, a0, a1, a2, sv);
        float m0 = a0, m1 = a1, m2 = a2;
#pragma unroll
        for (int off = 32; off >= 1; off >>= 1) {
            m0 = fmaxf(m0, __shfl_xor(m0, off));
            m1 = fmaxf(m1, __shfl_xor(m1, off));
            m2 = fmaxf(m2, __shfl_xor(m2, off));
        }
        float e0 = 0.f, e1 = 0.f, e2 = 0.f;
        if (lane < deg) {
            e0 = expf(a0 - m0);
            e1 = expf(a1 - m1);
            e2 = expf(a2 - m2);
        }
        float s0 = e0, s1 = e1, s2 = e2;
#pragma unroll
        for (int off = 32; off >= 1; off >>= 1) {
            s0 += __shfl_xor(s0, off);
            s1 += __shfl_xor(s1, off);
            s2 += __shfl_xor(s2, off);
        }
        float i0 = 1.f / (3.f * (s0 + 1e-16f));
        float i1 = 1.f / (3.f * (s1 + 1e-16f));
        float i2 = 1.f / (3.f * (s2 + 1e-16f));
        if (lane < deg)
            svw[beg + lane] = make_float4(__int_as_float(sv), e0 * i0, e1 * i1, e2 * i2);
    } else {
        float m0 = -INFINITY, m1 = -INFINITY, m2 = -INFINITY;
        for (int i = beg + lane; i < end; i += 64) {
            float a0, a1, a2; int sv;
            edge_alpha(i, ko, srcs, qkd, qbase, a0, a1, a2, sv);
            m0 = fmaxf(m0, a0); m1 = fmaxf(m1, a1); m2 = fmaxf(m2, a2);
        }
#pragma unroll
        for (int off = 32; off >= 1; off >>= 1) {
            m0 = fmaxf(m0, __shfl_xor(m0, off));
            m1 = fmaxf(m1, __shfl_xor(m1, off));
            m2 = fmaxf(m2, __shfl_xor(m2, off));
        }
        float s0 = 0.f, s1 = 0.f, s2 = 0.f;
        for (int i = beg + lane; i < end; i += 64) {
            float a0, a1, a2; int sv;
            edge_alpha(i, ko, srcs, qkd, qbase, a0, a1, a2, sv);
            s0 += expf(a0 - m0); s1 += expf(a1 - m1); s2 += expf(a2 - m2);
        }
#pragma unroll
        for (int off = 32; off >= 1; off >>= 1) {
            s0 += __shfl_xor(s0, off);
            s1 += __shfl_xor(s1, off);
            s2 += __shfl_xor(s2, off);
        }
        float i0 = 1.f / (3.f * (s0 + 1e-16f));
        float i1 = 1.f / (3.f * (s1 + 1e-16f));
        float i2 = 1.f / (3.f * (s2 + 1e-16f));
        for (int i = beg + lane; i < end; i += 64) {
            float a0, a1, a2; int sv;
            edge_alpha(i, ko, srcs, qkd, qbase, a0, a1, a2, sv);
            svw[i] = make_float4(__int_as_float(sv), expf(a0 - m0) * i0, expf(a1 - m1) * i1, expf(a2 - m2) * i2);
        }
    }
}

// ---------------- FUSED layer 1 v7: one rel per block + 4-deep batched gather ----------------
// grid (1250, 8). 16 nodes/block, quarter-wave per node.
#define PADK1 408
__global__ __launch_bounds__(256) void k_fused1(const int* __restrict__ keyoff, const float4* __restrict__ svw,
                                                const ushort_t* __restrict__ x, const ushort_t* __restrict__ wagg,
                                                float* __restrict__ part) {
    __shared__ ushort_t lt[16][PADK1];  // 12.75 KB (only LDS)
    const int tid = threadIdx.x;
    const int w = tid >> 6, lane = tid & 63;
    const int q15 = lane & 15, kq = (lane >> 4) * 8;
    const int l15 = lane & 15;
    const int nbase = blockIdx.x * 16;
    const int r = blockIdx.y;
    const int mynode = w * 4 + (lane >> 4);
    const int key = (nbase + mynode) * 8 + r;

    const int beg = keyoff[key], end = keyoff[key + 1];
    float a0[8] = {}, a1[8] = {}, a2[8] = {};
    for (int base = beg; base < end; base += BATCH) {
        float4 sw[BATCH];
#pragma unroll
        for (int u = 0; u < BATCH; u++) {
            int s = base + u;
            sw[u] = svw[s < end ? s : beg];      // independent, issue together
            if (s >= end) sw[u].y = sw[u].z = sw[u].w = 0.f;
        }
        ushort8_t xv[BATCH];
#pragma unroll
        for (int u = 0; u < BATCH; u++)          // independent gathers, issue together
            xv[u] = *(const ushort8_t*)&x[(size_t)__float_as_int(sw[u].x) * 128 + q15 * 8];
#pragma unroll
        for (int u = 0; u < BATCH; u++) {
#pragma unroll
            for (int c = 0; c < 8; c++) {
                float f = b2f(xv[u][c]);
                a0[c] += sw[u].y * f;
                a1[c] += sw[u].z * f;
                a2[c] += sw[u].w * f;
            }
        }
    }
    ushort8_t o0, o1, o2;
#pragma unroll
    for (int c = 0; c < 8; c++) {
        o0[c] = f2b(a0[c]);
        o1[c] = f2b(a1[c]);
        o2[c] = f2b(a2[c]);
    }
    *(ushort8_t*)&lt[mynode][0 * 128 + q15 * 8] = o0;
    *(ushort8_t*)&lt[mynode][1 * 128 + q15 * 8] = o1;
    *(ushort8_t*)&lt[mynode][2 * 128 + q15 * 8] = o2;
    __syncthreads();

    f32x4 acc = {};
#pragma unroll
    for (int ks = 0; ks < 12; ks++) {
        bf16x8 av = *(const bf16x8*)&lt[l15][ks * 32 + kq];
        bf16x8 bv = *(const bf16x8*)&wagg[(size_t)(w * 16 + l15) * 3072 + r * 384 + ks * 32 + kq];
        acc = __builtin_amdgcn_mfma_f32_16x16x32_bf16(av, bv, acc, 0, 0, 0);
    }
    float* op = part + (size_t)r * N_NODES * 64;
    const int r4 = (lane >> 4) * 4;
#pragma unroll
    for (int g = 0; g < 4; g++) {
        int row = nbase + r4 + g;
        op[(size_t)row * 64 + w * 16 + l15] = acc[g];
    }
}

// ---------------- FUSED layer 2 v7: one rel per block + batched gather ----------------
#define PADK2 208
__global__ __launch_bounds__(256) void k_fused2(const int* __restrict__ keyoff, const float4* __restrict__ svw,
                                                const ushort_t* __restrict__ x2in, const ushort_t* __restrict__ wagg,
                                                float* __restrict__ part) {
    __shared__ ushort_t lt[16][PADK2];  // 6.5 KB
    const int tid = threadIdx.x;
    const int w = tid >> 6, lane = tid & 63;
    const int q15 = lane & 15, kq = (lane >> 4) * 8;
    const int l15 = lane & 15;
    const int nbase = blockIdx.x * 16;
    const int r = blockIdx.y;
    const int mynode = w * 4 + (lane >> 4);
    const int key = (nbase + mynode) * 8 + r;

    const int beg = keyoff[key], end = keyoff[key + 1];
    float a0[4] = {}, a1[4] = {}, a2[4] = {};
    for (int base = beg; base < end; base += BATCH) {
        float4 sw[BATCH];
#pragma unroll
        for (int u = 0; u < BATCH; u++) {
            int s = base + u;
            sw[u] = svw[s < end ? s : beg];
            if (s >= end) sw[u].y = sw[u].z = sw[u].w = 0.f;
        }
        ushort4_t xv[BATCH];
#pragma unroll
        for (int u = 0; u < BATCH; u++)
            xv[u] = *(const ushort4_t*)&x2in[(size_t)__float_as_int(sw[u].x) * 64 + q15 * 4];
#pragma unroll
        for (int u = 0; u < BATCH; u++) {
#pragma unroll
            for (int c = 0; c < 4; c++) {
                float f = b2f(xv[u][c]);
                a0[c] += sw[u].y * f;
                a1[c] += sw[u].z * f;
                a2[c] += sw[u].w * f;
            }
        }
    }
    ushort4_t o0, o1, o2;
#pragma unroll
    for (int c = 0; c < 4; c++) {
        o0[c] = f2b(a0[c]);
        o1[c] = f2b(a1[c]);
        o2[c] = f2b(a2[c]);
    }
    *(ushort4_t*)&lt[mynode][0 * 64 + q15 * 4] = o0;
    *(ushort4_t*)&lt[mynode][1 * 64 + q15 * 4] = o1;
    *(ushort4_t*)&lt[mynode][2 * 64 + q15 * 4] = o2;
    __syncthreads();

    if (w == 0) {
        f32x4 acc = {};
#pragma unroll
        for (int ks = 0; ks < 6; ks++) {
            bf16x8 av = *(const bf16x8*)&lt[l15][ks * 32 + kq];
            bf16x8 bv = *(const bf16x8*)&wagg[(size_t)l15 * 1536 + r * 192 + ks * 32 + kq];
            acc = __builtin_amdgcn_mfma_f32_16x16x32_bf16(av, bv, acc, 0, 0, 0);
        }
        const int r4 = (lane >> 4) * 4;
#pragma unroll
        for (int g = 0; g < 4; g++)
            part[(size_t)r * N_NODES * 16 + (size_t)(nbase + r4 + g) * 16 + l15] = acc[g];
    }
}

// ---------------- 8-way partials reduce + bias + relu -> bf16 x2 ----------------
__global__ __launch_bounds__(256) void k_reduce1(const float* __restrict__ part, const float* __restrict__ bias,
                                                 ushort_t* __restrict__ x2) {
    int idx = blockIdx.x * blockDim.x + threadIdx.x;
    const int MN = N_NODES * 64;
    if (idx >= MN) return;
    float s = bias[idx & 63];
#pragma unroll
    for (int r = 0; r < 8; r++) s += part[idx + (size_t)r * MN];
    x2[idx] = f2b(s > 0.f ? s : 0.f);
}

// ---------------- 8-way partials reduce + bias + sigmoid -> out f32 ----------------
__global__ __launch_bounds__(256) void k_reduce2(const float* __restrict__ part, const float* __restrict__ bias,
                                                 float* __restrict__ outp) {
    int idx = blockIdx.x * blockDim.x + threadIdx.x;
    const int MN = N_NODES * 16;
    if (idx >= MN) return;
    float s = bias[idx & 15];
#pragma unroll
    for (int r = 0; r < 8; r++) s += part[idx + (size_t)r * MN];
    outp[idx] = 1.f / (1.f + expf(-s));
}

extern "C" void kernel_launch(void* const* d_in, const int* in_sizes, int n_in, void* d_out, int out_size,
                              void* d_ws, size_t ws_size, hipStream_t stream) {
    const float* emb = (const float*)d_in[0];
    const float* w1 = (const float*)d_in[1];
    const float* q1 = (const float*)d_in[2];
    const float* k1 = (const float*)d_in[3];
    const float* b1 = (const float*)d_in[4];
    const float* w2 = (const float*)d_in[5];
    const float* q2 = (const float*)d_in[6];
    const float* k2 = (const float*)d_in[7];
    const float* b2 = (const float*)d_in[8];
    const int* eidx = (const int*)d_in[9];
    const int* etype = (const int*)d_in[10];
    const int* srcv = eidx;
    const int* dstv = eidx + N_EDGES;
    float* out = (float*)d_out;

    char* p = (char*)d_ws;
    auto alloc = [&](size_t bytes) -> void* {
        void* q = p;
        p += (bytes + 255) & ~(size_t)255;
        return q;
    };
    int* counts = (int*)alloc((size_t)NKEYS * 4);
    int* keyoff = (int*)alloc((size_t)(NKEYS + 1) * 4);
    int* cursor = (int*)alloc((size_t)NKEYS * 4);
    int* blocksum = (int*)alloc((size_t)SCAN_NBLK * 4);
    int* blockbase = (int*)alloc((size_t)SCAN_NBLK * 4);
    int* srcs = (int*)alloc((size_t)N_EDGES * 4);
    float4* svw = (float4*)alloc((size_t)N_EDGES * 16);
    ushort_t* emb_b = (ushort_t*)alloc((size_t)N_NODES * EMB * 2);
    ushort_t* wqkt1 = (ushort_t*)alloc((size_t)48 * 128 * 2);
    ushort_t* wagg1 = (ushort_t*)alloc((size_t)64 * 3072 * 2);
    ushort_t* wqkt2 = (ushort_t*)alloc((size_t)48 * 64 * 2);
    ushort_t* wagg2 = (ushort_t*)alloc((size_t)16 * 1536 * 2);
    float* qkd = (float*)alloc((size_t)N_NODES * 48 * 4);
    ushort_t* x2 = (ushort_t*)alloc((size_t)N_NODES * 64 * 2);
    float* partials = (float*)alloc((size_t)8 * N_NODES * 64 * 4);

    // ---- precomputes ----
    k_cvt<<<(N_NODES * EMB / 4 + 255) / 256, 256, 0, stream>>>(emb, emb_b, N_NODES * EMB / 4);
    k_wqk<128, 192><<<(48 * 128 + 255) / 256, 256, 0, stream>>>(w1, q1, k1, wqkt1);
    k_wqk<64, 48><<<(48 * 64 + 255) / 256, 256, 0, stream>>>(w2, q2, k2, wqkt2);
    k_wagg<128, 64><<<(64 * 3072 + 255) / 256, 256, 0, stream>>>(w1, wagg1);
    k_wagg<64, 16><<<(16 * 1536 + 255) / 256, 256, 0, stream>>>(w2, wagg2);

    // ---- CSR over (dst, rel) ----
    hipMemsetAsync(counts, 0, (size_t)NKEYS * 4, stream);
    k_count<<<(N_EDGES + 255) / 256, 256, 0, stream>>>(dstv, etype, counts);
    k_scanA<<<SCAN_NBLK, 256, 0, stream>>>(counts, keyoff, blocksum);
    k_scanB<<<1, 256, 0, stream>>>(blocksum, blockbase, keyoff);
    k_scanC<<<SCAN_NBLK, 256, 0, stream>>>(blockbase, keyoff, cursor);
    k_scatter<<<(N_EDGES + 255) / 256, 256, 0, stream>>>(srcv, dstv, etype, cursor, srcs);

    // ---- layer 1 ----
    k_mfma_gemm<128, 128, 48, 1, 3><<<dim3(313, 1), 256, 0, stream>>>(emb_b, wqkt1, qkd, N_NODES);
    k_stats<<<N_NODES / 4, 256, 0, stream>>>(keyoff, srcs, qkd, svw);
    k_fused1<<<dim3(N_NODES / 16, 8), 256, 0, stream>>>(keyoff, svw, emb_b, wagg1, partials);
    k_reduce1<<<(N_NODES * 64 + 255) / 256, 256, 0, stream>>>(partials, b1, x2);

    // ---- layer 2 ----
    k_mfma_gemm<64, 64, 48, 1, 3><<<dim3(313, 1), 256, 0, stream>>>(x2, wqkt2, qkd, N_NODES);
    k_stats<<<N_NODES / 4, 256, 0, stream>>>(keyoff, srcs, qkd, svw);
    k_fused2<<<dim3(N_NODES / 16, 8), 256, 0, stream>>>(keyoff, svw, x2, wagg2, partials);
    k_reduce2<<<(N_NODES * 16 + 255) / 256, 256, 0, stream>>>(partials, b2, out);
}

// Round 12
// 243.760 us; speedup vs baseline: 1.2830x; 1.0516x over previous
//
#include <hip/hip_runtime.h>
#include <hip/hip_bf16.h>
#include <math.h>

#define N_NODES 20000
#define EMB 128
#define HID 64
#define RELS 8
#define CLS 16
#define N_EDGES 640000
#define NEG 0.2f
#define NKEYS (N_NODES * RELS)
#define SCAN_CHUNK 1024
#define SCAN_NBLK ((NKEYS + SCAN_CHUNK - 1) / SCAN_CHUNK)  // 157

typedef unsigned short ushort_t;
typedef __attribute__((ext_vector_type(8))) short bf16x8;
typedef __attribute__((ext_vector_type(8))) unsigned short ushort8_t;
typedef __attribute__((ext_vector_type(4))) unsigned short ushort4_t;
typedef __attribute__((ext_vector_type(4))) float f32x4;

__device__ __forceinline__ float b2f(ushort_t u) {
    return __uint_as_float(((unsigned int)u) << 16);
}
__device__ __forceinline__ ushort_t f2b(float f) {
    __hip_bfloat16 h = __float2bfloat16(f);
    return *reinterpret_cast<ushort_t*>(&h);
}

// ---------------- merged precompute: cvt + wqk1 + wqk2 + wagg1 + wagg2 ----------------
__device__ __forceinline__ void prep_cvt(int i, const float* __restrict__ in, ushort_t* __restrict__ outp) {
    float4 v = *(const float4*)&in[(size_t)i * 4];
    ushort4 o;
    o.x = f2b(v.x); o.y = f2b(v.y); o.z = f2b(v.z); o.w = f2b(v.w);
    *(ushort4*)&outp[(size_t)i * 4] = o;
}

template <int D, int OUT>
__device__ __forceinline__ void prep_wqk(int tid, const float* __restrict__ w, const float* __restrict__ q,
                                         const float* __restrict__ k, ushort_t* __restrict__ wqkt) {
    int c = tid / D, i = tid % D;
    int r = c / 6, j = c % 6;
    const float* qk = (j < 3) ? q : k;
    int jj = (j < 3) ? j : j - 3;
    const float* wrow = w + ((size_t)r * D + i) * OUT;
    float s = 0.f;
    for (int o = 0; o < OUT; o++) s += wrow[o] * qk[o * 3 + jj];
    wqkt[(size_t)c * D + i] = f2b(s);
}

template <int D, int OC>
__device__ __forceinline__ void prep_wagg(int tid, const float* __restrict__ w, ushort_t* __restrict__ outp) {
    const int KT = RELS * 3 * D;
    int kidx = tid % KT;
    int o = tid / KT;
    int r = kidx / (3 * D), h = (kidx / D) % 3, i = kidx % D;
    outp[tid] = f2b(w[((size_t)r * D + i) * (3 * OC) + h * OC + o]);
}

#define PREP_N0 (N_NODES * EMB / 4)
#define PREP_N1 (48 * 128)
#define PREP_N2 (48 * 64)
#define PREP_N3 (64 * 3072)
#define PREP_N4 (16 * 1536)
#define PREP_TOT (PREP_N0 + PREP_N1 + PREP_N2 + PREP_N3 + PREP_N4)

__global__ __launch_bounds__(256) void k_prep(const float* __restrict__ emb, ushort_t* __restrict__ emb_b,
                                              const float* __restrict__ w1, const float* __restrict__ q1,
                                              const float* __restrict__ k1, ushort_t* __restrict__ wqkt1,
                                              const float* __restrict__ w2, const float* __restrict__ q2,
                                              const float* __restrict__ k2, ushort_t* __restrict__ wqkt2,
                                              ushort_t* __restrict__ wagg1, ushort_t* __restrict__ wagg2) {
    int tid = blockIdx.x * 256 + threadIdx.x;
    if (tid < PREP_N0) { prep_cvt(tid, emb, emb_b); return; }
    tid -= PREP_N0;
    if (tid < PREP_N1) { prep_wqk<128, 192>(tid, w1, q1, k1, wqkt1); return; }
    tid -= PREP_N1;
    if (tid < PREP_N2) { prep_wqk<64, 48>(tid, w2, q2, k2, wqkt2); return; }
    tid -= PREP_N2;
    if (tid < PREP_N3) { prep_wagg<128, 64>(tid, w1, wagg1); return; }
    tid -= PREP_N3;
    if (tid < PREP_N4) { prep_wagg<64, 16>(tid, w2, wagg2); return; }
}

// ---------------- CSR build over keys = dst*8 + rel ----------------
__global__ __launch_bounds__(256) void k_count(const int* __restrict__ dst, const int* __restrict__ et,
                                               int* __restrict__ counts) {
    int e = blockIdx.x * blockDim.x + threadIdx.x;
    if (e < N_EDGES) atomicAdd(&counts[dst[e] * 8 + et[e]], 1);
}

__global__ __launch_bounds__(256) void k_scanA(const int* __restrict__ counts, int* __restrict__ keyoff,
                                               int* __restrict__ blocksum) {
    __shared__ int part[256];
    int b = blockIdx.x, tid = threadIdx.x;
    int base = b * SCAN_CHUNK + tid * 4;
    int4 c = make_int4(0, 0, 0, 0);
    if (base + 3 < NKEYS) c = *(const int4*)&counts[base];
    else {
        if (base + 0 < NKEYS) c.x = counts[base + 0];
        if (base + 1 < NKEYS) c.y = counts[base + 1];
        if (base + 2 < NKEYS) c.z = counts[base + 2];
        if (base + 3 < NKEYS) c.w = counts[base + 3];
    }
    int s = c.x + c.y + c.z + c.w;
    part[tid] = s;
    __syncthreads();
    for (int off = 1; off < 256; off <<= 1) {
        int v = (tid >= off) ? part[tid - off] : 0;
        __syncthreads();
        part[tid] += v;
        __syncthreads();
    }
    int excl = part[tid] - s;
    int4 o;
    o.x = excl;
    o.y = excl + c.x;
    o.z = excl + c.x + c.y;
    o.w = excl + c.x + c.y + c.z;
    if (base + 3 < NKEYS) *(int4*)&keyoff[base] = o;
    else {
        if (base + 0 < NKEYS) keyoff[base + 0] = o.x;
        if (base + 1 < NKEYS) keyoff[base + 1] = o.y;
        if (base + 2 < NKEYS) keyoff[base + 2] = o.z;
        if (base + 3 < NKEYS) keyoff[base + 3] = o.w;
    }
    if (tid == 255) blocksum[b] = part[255];
}

__global__ __launch_bounds__(256) void k_scanB(int* __restrict__ blocksum, int* __restrict__ blockbase,
                                               int* __restrict__ keyoff) {
    __shared__ int part[256];
    int tid = threadIdx.x;
    int v0 = (tid < SCAN_NBLK) ? blocksum[tid] : 0;
    part[tid] = v0;
    __syncthreads();
    for (int off = 1; off < 256; off <<= 1) {
        int v = (tid >= off) ? part[tid - off] : 0;
        __syncthreads();
        part[tid] += v;
        __syncthreads();
    }
    if (tid < SCAN_NBLK) blockbase[tid] = part[tid] - v0;
    if (tid == 255) keyoff[NKEYS] = part[255];
}

__global__ __launch_bounds__(256) void k_scanC(const int* __restrict__ blockbase, int* __restrict__ keyoff,
                                               int* __restrict__ cursor) {
    int b = blockIdx.x, tid = threadIdx.x;
    int base = b * SCAN_CHUNK + tid * 4;
    int add = blockbase[b];
    if (base + 3 < NKEYS) {
        int4 v = *(const int4*)&keyoff[base];
        v.x += add; v.y += add; v.z += add; v.w += add;
        *(int4*)&keyoff[base] = v;
        *(int4*)&cursor[base] = v;
    } else {
        for (int j = 0; j < 4; j++) {
            if (base + j < NKEYS) {
                int v = keyoff[base + j] + add;
                keyoff[base + j] = v;
                cursor[base + j] = v;
            }
        }
    }
}

// ---------------- scatter srcs into CSR order ----------------
__global__ __launch_bounds__(256) void k_scatter(const int* __restrict__ src, const int* __restrict__ dst,
                                                 const int* __restrict__ et, int* __restrict__ cursor,
                                                 int* __restrict__ srcs) {
    int e = blockIdx.x * blockDim.x + threadIdx.x;
    if (e < N_EDGES) {
        int p = atomicAdd(&cursor[dst[e] * 8 + et[e]], 1);
        srcs[p] = src[e];
    }
}

// ---------------- direct-fragment MFMA GEMM (qkd projections) ----------------
template <int K, int KCH, int N, int MREP, int NREP>
__global__ __launch_bounds__(256) void k_mfma_gemm(const ushort_t* __restrict__ A, const ushort_t* __restrict__ Bt,
                                                   float* __restrict__ outp, int M) {
    const int wid = threadIdx.x >> 6;
    const int lane = threadIdx.x & 63;
    const int m0 = blockIdx.x * (4 * MREP * 16) + wid * (MREP * 16);
    const int kbase = blockIdx.y * KCH;
    const int l15 = lane & 15;
    const int kq = (lane >> 4) * 8;

    f32x4 acc[MREP][NREP] = {};
    for (int kk = kbase; kk < kbase + KCH; kk += 32) {
        bf16x8 a[MREP], b[NREP];
#pragma unroll
        for (int i = 0; i < MREP; i++) {
            int row = m0 + i * 16 + l15;
            row = row < M ? row : M - 1;
            a[i] = *(const bf16x8*)&A[(size_t)row * K + kk + kq];
        }
#pragma unroll
        for (int j = 0; j < NREP; j++) b[j] = *(const bf16x8*)&Bt[(size_t)(j * 16 + l15) * K + kk + kq];
#pragma unroll
        for (int i = 0; i < MREP; i++)
#pragma unroll
            for (int j = 0; j < NREP; j++)
                acc[i][j] = __builtin_amdgcn_mfma_f32_16x16x32_bf16(a[i], b[j], acc[i][j], 0, 0, 0);
    }
    float* op = outp + (size_t)blockIdx.y * M * N;
    const int r4 = (lane >> 4) * 4;
#pragma unroll
    for (int i = 0; i < MREP; i++) {
#pragma unroll
        for (int j = 0; j < NREP; j++) {
#pragma unroll
            for (int g = 0; g < 4; g++) {
                int row = m0 + i * 16 + r4 + g;
                if (row < M) op[(size_t)row * N + j * 16 + l15] = acc[i][j][g];
            }
        }
    }
}

// ---------------- per-edge alpha from qkd (on the fly), also returns src ----------------
__device__ __forceinline__ void edge_alpha(int s_idx, const int (&ko)[9], const int* __restrict__ srcs,
                                           const float* __restrict__ qkd, const float* __restrict__ qbase,
                                           float& a0, float& a1, float& a2, int& sv) {
    int r = 0;
#pragma unroll
    for (int j = 1; j < 8; j++) r += (s_idx >= ko[j]) ? 1 : 0;
    sv = srcs[s_idx];
    const float* kd = qkd + (size_t)sv * 48 + r * 6 + 3;
    const float* qd = qbase + r * 6;
    float t0 = qd[0] + kd[0], t1 = qd[1] + kd[1], t2 = qd[2] + kd[2];
    a0 = t0 > 0.f ? t0 : NEG * t0;
    a1 = t1 > 0.f ? t1 : NEG * t1;
    a2 = t2 > 0.f ? t2 : NEG * t2;
}

// ---------------- softmax stats -> svw[e] = {src_bits, w0, w1, w2} ----------------
__global__ __launch_bounds__(256) void k_stats(const int* __restrict__ keyoff, const int* __restrict__ srcs,
                                               const float* __restrict__ qkd, float4* __restrict__ svw) {
    int node = blockIdx.x * 4 + (threadIdx.x >> 6);
    int lane = threadIdx.x & 63;
    int ko[9];
#pragma unroll
    for (int j = 0; j < 9; j++) ko[j] = keyoff[node * 8 + j];
    int beg = ko[0], end = ko[8], deg = end - beg;
    if (deg == 0) return;
    const float* qbase = qkd + (size_t)node * 48;

    if (deg <= 64) {
        float a0 = -INFINITY, a1 = -INFINITY, a2 = -INFINITY;
        int sv = 0;
        if (lane < deg) edge_alpha(beg + lane, ko, srcs, qkd, qbase, a0, a1, a2, sv);
        float m0 = a0, m1 = a1, m2 = a2;
#pragma unroll
        for (int off = 32; off >= 1; off >>= 1) {
            m0 = fmaxf(m0, __shfl_xor(m0, off));
            m1 = fmaxf(m1, __shfl_xor(m1, off));
            m2 = fmaxf(m2, __shfl_xor(m2, off));
        }
        float e0 = 0.f, e1 = 0.f, e2 = 0.f;
        if (lane < deg) {
            e0 = expf(a0 - m0);
            e1 = expf(a1 - m1);
            e2 = expf(a2 - m2);
        }
        float s0 = e0, s1 = e1, s2 = e2;
#pragma unroll
        for (int off = 32; off >= 1; off >>= 1) {
            s0 += __shfl_xor(s0, off);
            s1 += __shfl_xor(s1, off);
            s2 += __shfl_xor(s2, off);
        }
        float i0 = 1.f / (3.f * (s0 + 1e-16f));
        float i1 = 1.f / (3.f * (s1 + 1e-16f));
        float i2 = 1.f / (3.f * (s2 + 1e-16f));
        if (lane < deg)
            svw[beg + lane] = make_float4(__int_as_float(sv), e0 * i0, e1 * i1, e2 * i2);
    } else {
        float m0 = -INFINITY, m1 = -INFINITY, m2 = -INFINITY;
        for (int i = beg + lane; i < end; i += 64) {
            float a0, a1, a2; int sv;
            edge_alpha(i, ko, srcs, qkd, qbase, a0, a1, a2, sv);
            m0 = fmaxf(m0, a0); m1 = fmaxf(m1, a1); m2 = fmaxf(m2, a2);
        }
#pragma unroll
        for (int off = 32; off >= 1; off >>= 1) {
            m0 = fmaxf(m0, __shfl_xor(m0, off));
            m1 = fmaxf(m1, __shfl_xor(m1, off));
            m2 = fmaxf(m2, __shfl_xor(m2, off));
        }
        float s0 = 0.f, s1 = 0.f, s2 = 0.f;
        for (int i = beg + lane; i < end; i += 64) {
            float a0, a1, a2; int sv;
            edge_alpha(i, ko, srcs, qkd, qbase, a0, a1, a2, sv);
            s0 += expf(a0 - m0); s1 += expf(a1 - m1); s2 += expf(a2 - m2);
        }
#pragma unroll
        for (int off = 32; off >= 1; off >>= 1) {
            s0 += __shfl_xor(s0, off);
            s1 += __shfl_xor(s1, off);
            s2 += __shfl_xor(s2, off);
        }
        float i0 = 1.f / (3.f * (s0 + 1e-16f));
        float i1 = 1.f / (3.f * (s1 + 1e-16f));
        float i2 = 1.f / (3.f * (s2 + 1e-16f));
        for (int i = beg + lane; i < end; i += 64) {
            float a0, a1, a2; int sv;
            edge_alpha(i, ko, srcs, qkd, qbase, a0, a1, a2, sv);
            svw[i] = make_float4(__int_as_float(sv), expf(a0 - m0) * i0, expf(a1 - m1) * i1, expf(a2 - m2) * i2);
        }
    }
}

// ---------------- FUSED layer 1 v8: one rel per block + 2-ahead pipelined gather ----------------
// grid (1250, 8). 16 nodes/block, quarter-wave per node.
#define PADK1 408
__global__ __launch_bounds__(256) void k_fused1(const int* __restrict__ keyoff, const float4* __restrict__ svw,
                                                const ushort_t* __restrict__ x, const ushort_t* __restrict__ wagg,
                                                float* __restrict__ part) {
    __shared__ ushort_t lt[16][PADK1];  // 12.75 KB (only LDS)
    const int tid = threadIdx.x;
    const int w = tid >> 6, lane = tid & 63;
    const int q15 = lane & 15, kq = (lane >> 4) * 8;
    const int l15 = lane & 15;
    const int nbase = blockIdx.x * 16;
    const int r = blockIdx.y;
    const int mynode = w * 4 + (lane >> 4);
    const int key = (nbase + mynode) * 8 + r;

    const int beg = keyoff[key], end = keyoff[key + 1];
    const int deg = end - beg;
    float a0[8] = {}, a1[8] = {}, a2[8] = {};
    if (deg > 0) {
        // 2-ahead software pipeline: sw0 (consume), sw1 (gather now), sw2 (load now)
        float4 sw0 = svw[beg];
        float4 sw1;
        {
            int s = beg + 1;
            sw1 = svw[s < end ? s : beg];
            if (1 >= deg) { sw1.y = 0.f; sw1.z = 0.f; sw1.w = 0.f; }
        }
        ushort8_t xv0 = *(const ushort8_t*)&x[(size_t)__float_as_int(sw0.x) * 128 + q15 * 8];
        for (int i = 0; i < deg; i++) {
            float4 sw2;
            {
                int s = beg + i + 2;
                sw2 = svw[s < end ? s : beg];
                if (i + 2 >= deg) { sw2.y = 0.f; sw2.z = 0.f; sw2.w = 0.f; }
            }
            ushort8_t xv1 = *(const ushort8_t*)&x[(size_t)__float_as_int(sw1.x) * 128 + q15 * 8];
#pragma unroll
            for (int c = 0; c < 8; c++) {
                float f = b2f(xv0[c]);
                a0[c] += sw0.y * f;
                a1[c] += sw0.z * f;
                a2[c] += sw0.w * f;
            }
            sw0 = sw1;
            sw1 = sw2;
            xv0 = xv1;
        }
    }
    ushort8_t o0, o1, o2;
#pragma unroll
    for (int c = 0; c < 8; c++) {
        o0[c] = f2b(a0[c]);
        o1[c] = f2b(a1[c]);
        o2[c] = f2b(a2[c]);
    }
    *(ushort8_t*)&lt[mynode][0 * 128 + q15 * 8] = o0;
    *(ushort8_t*)&lt[mynode][1 * 128 + q15 * 8] = o1;
    *(ushort8_t*)&lt[mynode][2 * 128 + q15 * 8] = o2;
    __syncthreads();

    f32x4 acc = {};
#pragma unroll
    for (int ks = 0; ks < 12; ks++) {
        bf16x8 av = *(const bf16x8*)&lt[l15][ks * 32 + kq];
        bf16x8 bv = *(const bf16x8*)&wagg[(size_t)(w * 16 + l15) * 3072 + r * 384 + ks * 32 + kq];
        acc = __builtin_amdgcn_mfma_f32_16x16x32_bf16(av, bv, acc, 0, 0, 0);
    }
    float* op = part + (size_t)r * N_NODES * 64;
    const int r4 = (lane >> 4) * 4;
#pragma unroll
    for (int g = 0; g < 4; g++) {
        int row = nbase + r4 + g;
        op[(size_t)row * 64 + w * 16 + l15] = acc[g];
    }
}

// ---------------- FUSED layer 2 v8: one rel per block + pipelined gather ----------------
#define PADK2 208
__global__ __launch_bounds__(256) void k_fused2(const int* __restrict__ keyoff, const float4* __restrict__ svw,
                                                const ushort_t* __restrict__ x2in, const ushort_t* __restrict__ wagg,
                                                float* __restrict__ part) {
    __shared__ ushort_t lt[16][PADK2];  // 6.5 KB
    const int tid = threadIdx.x;
    const int w = tid >> 6, lane = tid & 63;
    const int q15 = lane & 15, kq = (lane >> 4) * 8;
    const int l15 = lane & 15;
    const int nbase = blockIdx.x * 16;
    const int r = blockIdx.y;
    const int mynode = w * 4 + (lane >> 4);
    const int key = (nbase + mynode) * 8 + r;

    const int beg = keyoff[key], end = keyoff[key + 1];
    const int deg = end - beg;
    float a0[4] = {}, a1[4] = {}, a2[4] = {};
    if (deg > 0) {
        float4 sw0 = svw[beg];
        float4 sw1;
        {
            int s = beg + 1;
            sw1 = svw[s < end ? s : beg];
            if (1 >= deg) { sw1.y = 0.f; sw1.z = 0.f; sw1.w = 0.f; }
        }
        ushort4_t xv0 = *(const ushort4_t*)&x2in[(size_t)__float_as_int(sw0.x) * 64 + q15 * 4];
        for (int i = 0; i < deg; i++) {
            float4 sw2;
            {
                int s = beg + i + 2;
                sw2 = svw[s < end ? s : beg];
                if (i + 2 >= deg) { sw2.y = 0.f; sw2.z = 0.f; sw2.w = 0.f; }
            }
            ushort4_t xv1 = *(const ushort4_t*)&x2in[(size_t)__float_as_int(sw1.x) * 64 + q15 * 4];
#pragma unroll
            for (int c = 0; c < 4; c++) {
                float f = b2f(xv0[c]);
                a0[c] += sw0.y * f;
                a1[c] += sw0.z * f;
                a2[c] += sw0.w * f;
            }
            sw0 = sw1;
            sw1 = sw2;
            xv0 = xv1;
        }
    }
    ushort4_t o0, o1, o2;
#pragma unroll
    for (int c = 0; c < 4; c++) {
        o0[c] = f2b(a0[c]);
        o1[c] = f2b(a1[c]);
        o2[c] = f2b(a2[c]);
    }
    *(ushort4_t*)&lt[mynode][0 * 64 + q15 * 4] = o0;
    *(ushort4_t*)&lt[mynode][1 * 64 + q15 * 4] = o1;
    *(ushort4_t*)&lt[mynode][2 * 64 + q15 * 4] = o2;
    __syncthreads();

    if (w == 0) {
        f32x4 acc = {};
#pragma unroll
        for (int ks = 0; ks < 6; ks++) {
            bf16x8 av = *(const bf16x8*)&lt[l15][ks * 32 + kq];
            bf16x8 bv = *(const bf16x8*)&wagg[(size_t)l15 * 1536 + r * 192 + ks * 32 + kq];
            acc = __builtin_amdgcn_mfma_f32_16x16x32_bf16(av, bv, acc, 0, 0, 0);
        }
        const int r4 = (lane >> 4) * 4;
#pragma unroll
        for (int g = 0; g < 4; g++)
            part[(size_t)r * N_NODES * 16 + (size_t)(nbase + r4 + g) * 16 + l15] = acc[g];
    }
}

// ---------------- 8-way partials reduce + bias + relu -> bf16 x2 ----------------
__global__ __launch_bounds__(256) void k_reduce1(const float* __restrict__ part, const float* __restrict__ bias,
                                                 ushort_t* __restrict__ x2) {
    int idx = blockIdx.x * blockDim.x + threadIdx.x;
    const int MN = N_NODES * 64;
    if (idx >= MN) return;
    float s = bias[idx & 63];
#pragma unroll
    for (int r = 0; r < 8; r++) s += part[idx + (size_t)r * MN];
    x2[idx] = f2b(s > 0.f ? s : 0.f);
}

// ---------------- 8-way partials reduce + bias + sigmoid -> out f32 ----------------
__global__ __launch_bounds__(256) void k_reduce2(const float* __restrict__ part, const float* __restrict__ bias,
                                                 float* __restrict__ outp) {
    int idx = blockIdx.x * blockDim.x + threadIdx.x;
    const int MN = N_NODES * 16;
    if (idx >= MN) return;
    float s = bias[idx & 15];
#pragma unroll
    for (int r = 0; r < 8; r++) s += part[idx + (size_t)r * MN];
    outp[idx] = 1.f / (1.f + expf(-s));
}

extern "C" void kernel_launch(void* const* d_in, const int* in_sizes, int n_in, void* d_out, int out_size,
                              void* d_ws, size_t ws_size, hipStream_t stream) {
    const float* emb = (const float*)d_in[0];
    const float* w1 = (const float*)d_in[1];
    const float* q1 = (const float*)d_in[2];
    const float* k1 = (const float*)d_in[3];
    const float* b1 = (const float*)d_in[4];
    const float* w2 = (const float*)d_in[5];
    const float* q2 = (const float*)d_in[6];
    const float* k2 = (const float*)d_in[7];
    const float* b2 = (const float*)d_in[8];
    const int* eidx = (const int*)d_in[9];
    const int* etype = (const int*)d_in[10];
    const int* srcv = eidx;
    const int* dstv = eidx + N_EDGES;
    float* out = (float*)d_out;

    char* p = (char*)d_ws;
    auto alloc = [&](size_t bytes) -> void* {
        void* q = p;
        p += (bytes + 255) & ~(size_t)255;
        return q;
    };
    int* counts = (int*)alloc((size_t)NKEYS * 4);
    int* keyoff = (int*)alloc((size_t)(NKEYS + 1) * 4);
    int* cursor = (int*)alloc((size_t)NKEYS * 4);
    int* blocksum = (int*)alloc((size_t)SCAN_NBLK * 4);
    int* blockbase = (int*)alloc((size_t)SCAN_NBLK * 4);
    int* srcs = (int*)alloc((size_t)N_EDGES * 4);
    float4* svw = (float4*)alloc((size_t)N_EDGES * 16);
    ushort_t* emb_b = (ushort_t*)alloc((size_t)N_NODES * EMB * 2);
    ushort_t* wqkt1 = (ushort_t*)alloc((size_t)48 * 128 * 2);
    ushort_t* wagg1 = (ushort_t*)alloc((size_t)64 * 3072 * 2);
    ushort_t* wqkt2 = (ushort_t*)alloc((size_t)48 * 64 * 2);
    ushort_t* wagg2 = (ushort_t*)alloc((size_t)16 * 1536 * 2);
    float* qkd = (float*)alloc((size_t)N_NODES * 48 * 4);
    ushort_t* x2 = (ushort_t*)alloc((size_t)N_NODES * 64 * 2);
    float* partials = (float*)alloc((size_t)8 * N_NODES * 64 * 4);

    // ---- merged precomputes ----
    k_prep<<<(PREP_TOT + 255) / 256, 256, 0, stream>>>(emb, emb_b, w1, q1, k1, wqkt1, w2, q2, k2, wqkt2, wagg1,
                                                       wagg2);

    // ---- CSR over (dst, rel) ----
    hipMemsetAsync(counts, 0, (size_t)NKEYS * 4, stream);
    k_count<<<(N_EDGES + 255) / 256, 256, 0, stream>>>(dstv, etype, counts);
    k_scanA<<<SCAN_NBLK, 256, 0, stream>>>(counts, keyoff, blocksum);
    k_scanB<<<1, 256, 0, stream>>>(blocksum, blockbase, keyoff);
    k_scanC<<<SCAN_NBLK, 256, 0, stream>>>(blockbase, keyoff, cursor);
    k_scatter<<<(N_EDGES + 255) / 256, 256, 0, stream>>>(srcv, dstv, etype, cursor, srcs);

    // ---- layer 1 ----
    k_mfma_gemm<128, 128, 48, 1, 3><<<dim3(313, 1), 256, 0, stream>>>(emb_b, wqkt1, qkd, N_NODES);
    k_stats<<<N_NODES / 4, 256, 0, stream>>>(keyoff, srcs, qkd, svw);
    k_fused1<<<dim3(N_NODES / 16, 8), 256, 0, stream>>>(keyoff, svw, emb_b, wagg1, partials);
    k_reduce1<<<(N_NODES * 64 + 255) / 256, 256, 0, stream>>>(partials, b1, x2);

    // ---- layer 2 ----
    k_mfma_gemm<64, 64, 48, 1, 3><<<dim3(313, 1), 256, 0, stream>>>(x2, wqkt2, qkd, N_NODES);
    k_stats<<<N_NODES / 4, 256, 0, stream>>>(keyoff, srcs, qkd, svw);
    k_fused2<<<dim3(N_NODES / 16, 8), 256, 0, stream>>>(keyoff, svw, x2, wagg2, partials);
    k_reduce2<<<(N_NODES * 16 + 255) / 256, 256, 0, stream>>>(partials, b2, out);
}